// Round 14
// baseline (4659.611 us; speedup 1.0000x reference)
//
#include <hip/hip_runtime.h>
#include <cstdint>
#include <cstddef>

#define DEV static __device__ __forceinline__

typedef unsigned short u16;
typedef unsigned int   u32;
typedef __bf16 bf16x8 __attribute__((ext_vector_type(8)));
typedef float  f32x4  __attribute__((ext_vector_type(4)));

namespace {
constexpr int NB     = 8;
constexpr int NT     = 1024;
constexpr int NMEL   = 96;
constexpr int NDIM   = 192;
constexpr int NCH    = 32;
constexpr int DMODEL = 1536;
constexpr int DINNER = 3072;
constexpr int DSTATE = 16;
constexpr int DTRANK = 96;
constexpr int NLAYER = 4;
constexpr int NCLASS = 5;
constexpr int MROWS  = NB * NT;   // 8192
constexpr int NCHK   = 16;
constexpr int CHKT   = NT / NCHK; // 64
}

DEV float siluf(float x)    { return x / (1.0f + __expf(-x)); }
DEV float softplusf(float x){ return fmaxf(x, 0.0f) + log1pf(__expf(-fabsf(x))); }

DEV u16 f2bf(float f) {
    u32 u = __float_as_uint(f);
    u32 r = u + 0x7FFFu + ((u >> 16) & 1u);
    return (u16)(r >> 16);
}
DEV float bf2f(u16 h) { return __uint_as_float(((u32)h) << 16); }

DEV f32x4 exp2v(f32x4 x) {
    f32x4 r;
    r[0] = exp2f(x[0]); r[1] = exp2f(x[1]);
    r[2] = exp2f(x[2]); r[3] = exp2f(x[3]);
    return r;
}

#define GLD(gp, lp) __builtin_amdgcn_global_load_lds( \
    (const __attribute__((address_space(1))) u32*)(const void*)(gp), \
    (__attribute__((address_space(3))) u32*)(void*)(lp), 16, 0, 0)

// ---------------- prep: x -> hcat (B,192,T): [x ; relu(diff)]; also zero ZPAD ----------------
__global__ __launch_bounds__(256) void k_prep(const float* __restrict__ x,
                                              float* __restrict__ hcat,
                                              u16* __restrict__ zpad)
{
    if (blockIdx.x == 0 && threadIdx.x < 128) zpad[threadIdx.x] = 0;
    int idx = blockIdx.x * 256 + threadIdx.x;
    if (idx >= NB * NDIM * NT) return;
    int t = idx & (NT - 1);
    int m = (idx >> 10) % NDIM;
    int b = idx / (NDIM * NT);
    float v;
    if (m < NMEL) {
        v = x[((size_t)b * NMEL + m) * NT + t];
    } else {
        int mm = m - NMEL;
        v = 0.f;
        if (t > 0) {
            const float* p = x + ((size_t)b * NMEL + mm) * NT + t;
            v = fmaxf(p[0] - p[-1], 0.f);
        }
    }
    hcat[idx] = v;
}

// ---------------- conv weight prep x3: (32,32,3,3) -> [tap][cout][ci] hi/lo ----------------
__global__ __launch_bounds__(256) void k_wconv3(
    const float* __restrict__ w0, u16* __restrict__ dh0, u16* __restrict__ dl0,
    const float* __restrict__ w1, u16* __restrict__ dh1, u16* __restrict__ dl1,
    const float* __restrict__ w2, u16* __restrict__ dh2, u16* __restrict__ dl2)
{
    int idx = blockIdx.x * 256 + threadIdx.x;
    if (idx >= 9216) return;
    const float* w = (blockIdx.y == 0) ? w0 : (blockIdx.y == 1) ? w1 : w2;
    u16* dh = (blockIdx.y == 0) ? dh0 : (blockIdx.y == 1) ? dh1 : dh2;
    u16* dl = (blockIdx.y == 0) ? dl0 : (blockIdx.y == 1) ? dl1 : dl2;
    int ci = idx & 31, cout = (idx >> 5) & 31, tap = idx >> 10;
    float v = w[((size_t)cout * 32 + ci) * 9 + tap];
    u16 h = f2bf(v);
    dh[idx] = h;
    dl[idx] = f2bf(v - bf2f(h));
}

// ---------------- conv1a (1->32, 3x3) + silu -> NHWC bf16 hi/lo ----------------
__global__ __launch_bounds__(256) void k_conv1a(const float* __restrict__ hcat,
    const float* __restrict__ w, const float* __restrict__ bias,
    u16* __restrict__ oh, u16* __restrict__ ol)   // (B,192,T,32)
{
    int idx = blockIdx.x * 256 + threadIdx.x;
    if (idx >= NB * NDIM * NT) return;
    int t = idx & (NT - 1);
    int h = (idx >> 10) % NDIM;
    int b = idx / (NDIM * NT);
    float in[3][3];
    #pragma unroll
    for (int dh = 0; dh < 3; ++dh)
        #pragma unroll
        for (int dw = 0; dw < 3; ++dw) {
            int hh = h + dh - 1, tt = t + dw - 1;
            in[dh][dw] = (hh >= 0 && hh < NDIM && tt >= 0 && tt < NT)
                       ? hcat[((size_t)b * NDIM + hh) * NT + tt] : 0.f;
        }
    u16 hb[32], lb[32];
    #pragma unroll
    for (int c = 0; c < NCH; ++c) {
        float acc = bias[c];
        #pragma unroll
        for (int dh = 0; dh < 3; ++dh)
            #pragma unroll
            for (int dw = 0; dw < 3; ++dw)
                acc = fmaf(in[dh][dw], w[c * 9 + dh * 3 + dw], acc);
        float o = siluf(acc);
        u16 hh2 = f2bf(o);
        hb[c] = hh2;
        lb[c] = f2bf(o - bf2f(hh2));
    }
    size_t ob = (((size_t)b * NDIM + h) * NT + t) * 32;
    #pragma unroll
    for (int j = 0; j < 8; ++j) {
        ushort4 hv = { hb[j*4], hb[j*4+1], hb[j*4+2], hb[j*4+3] };
        ushort4 lv = { lb[j*4], lb[j*4+1], lb[j*4+2], lb[j*4+3] };
        *(ushort4*)(oh + ob + j * 4) = hv;
        *(ushort4*)(ol + ob + j * 4) = lv;
    }
}

// ---------------- MFMA implicit-GEMM conv 32->32 3x3 (NHWC bf16 hi/lo) ----------------
template<int VAR>
__global__ __launch_bounds__(256) void k_convmfma(
    const u16* __restrict__ Xh, const u16* __restrict__ Xl,
    const u16* __restrict__ CWh, const u16* __restrict__ CWl,
    const float* __restrict__ hcat, const float* __restrict__ sw, const float* __restrict__ sb,
    const u16* __restrict__ Sh, const u16* __restrict__ Sl,
    const float* __restrict__ bias,
    u16* __restrict__ Oh, u16* __restrict__ Ol,
    float* __restrict__ RES,
    const u16* __restrict__ zeropad)
{
    constexpr int HIN = (VAR == 0) ? 192 : 96;
    __shared__ __align__(16) u16 lds[2][8448];
    const int t0 = blockIdx.x * 64;
    const int ho = blockIdx.y;
    const int b  = blockIdx.z;
    const int tid = threadIdx.x;
    const int wid = tid >> 6, lane = tid & 63;
    const int r0 = 2 * ho - 1;

    for (int cb = wid * 64; cb < 2112; cb += 256) {
        int c = cb + lane;
        int plane = (c >= 1056) ? 1 : 0;
        int cc = c - plane * 1056;
        int row = cc / 264;
        int rc  = cc - row * 264;
        int pos = rc >> 2;
        int slot = rc & 3;
        int cib = slot ^ ((pos >> 1) & 3);
        int h = r0 + row;
        int t = t0 - 1 + pos;
        const u16* bp = plane ? Xl : Xh;
        const u16* src = (h >= 0 && h < HIN && t >= 0 && t < NT)
            ? bp + (((size_t)(b * HIN + h)) * NT + t) * 32 + cib * 8
            : zeropad;
        u16* ldst = &lds[0][0] + (size_t)cb * 8;
        GLD(src, ldst);
    }
    __syncthreads();

    const int fr = lane & 15, fq = lane >> 4;
    f32x4 acc[2][2];
    #pragma unroll
    for (int pr = 0; pr < 2; ++pr)
        #pragma unroll
        for (int mt = 0; mt < 2; ++mt) acc[pr][mt] = (f32x4){0.f, 0.f, 0.f, 0.f};

    #pragma unroll
    for (int dh = 0; dh < 3; ++dh) {
        #pragma unroll
        for (int dt = 0; dt < 3; ++dt) {
            int tap = dh * 3 + dt;
            bf16x8 wh[2], wl[2];
            #pragma unroll
            for (int mt = 0; mt < 2; ++mt) {
                size_t wo = ((size_t)tap * 32 + mt * 16 + fr) * 32 + fq * 8;
                wh[mt] = *(const bf16x8*)(CWh + wo);
                wl[mt] = *(const bf16x8*)(CWl + wo);
            }
            int p = (wid << 4) + fr + dt;
            int sl = fq ^ ((p >> 1) & 3);
            #pragma unroll
            for (int pr = 0; pr < 2; ++pr) {
                int rr = pr + dh;
                const u16* lp = &lds[0][0] + ((rr * 66 + p) * 4 + sl) * 8;
                bf16x8 xh = *(const bf16x8*)lp;
                bf16x8 xl = *(const bf16x8*)(lp + 8448);
                #pragma unroll
                for (int mt = 0; mt < 2; ++mt) {
                    acc[pr][mt] = __builtin_amdgcn_mfma_f32_16x16x32_bf16(wh[mt], xh, acc[pr][mt], 0, 0, 0);
                    acc[pr][mt] = __builtin_amdgcn_mfma_f32_16x16x32_bf16(wh[mt], xl, acc[pr][mt], 0, 0, 0);
                    acc[pr][mt] = __builtin_amdgcn_mfma_f32_16x16x32_bf16(wl[mt], xh, acc[pr][mt], 0, 0, 0);
                }
            }
        }
    }

    const int t = t0 + (wid << 4) + fr;
    float hc0 = 0.f, hc1 = 0.f;
    if (VAR == 0) {
        hc0 = hcat[((size_t)(b * NDIM + 2 * ho    )) * NT + t];
        hc1 = hcat[((size_t)(b * NDIM + 2 * ho + 1)) * NT + t];
    }
    #pragma unroll
    for (int mt = 0; mt < 2; ++mt) {
        float v0[4], v1[4];
        if (VAR == 2) {
            ushort4 s0h = *(const ushort4*)(Sh + (((size_t)(b * 96 + 2 * ho    )) * NT + t) * 32 + mt * 16 + fq * 4);
            ushort4 s0l = *(const ushort4*)(Sl + (((size_t)(b * 96 + 2 * ho    )) * NT + t) * 32 + mt * 16 + fq * 4);
            ushort4 s1h = *(const ushort4*)(Sh + (((size_t)(b * 96 + 2 * ho + 1)) * NT + t) * 32 + mt * 16 + fq * 4);
            ushort4 s1l = *(const ushort4*)(Sl + (((size_t)(b * 96 + 2 * ho + 1)) * NT + t) * 32 + mt * 16 + fq * 4);
            v0[0] = bf2f(s0h.x) + bf2f(s0l.x); v0[1] = bf2f(s0h.y) + bf2f(s0l.y);
            v0[2] = bf2f(s0h.z) + bf2f(s0l.z); v0[3] = bf2f(s0h.w) + bf2f(s0l.w);
            v1[0] = bf2f(s1h.x) + bf2f(s1l.x); v1[1] = bf2f(s1h.y) + bf2f(s1l.y);
            v1[2] = bf2f(s1h.z) + bf2f(s1l.z); v1[3] = bf2f(s1h.w) + bf2f(s1l.w);
        }
        u16 hs[4], ls[4];
        float r0v[4], r1v[4];
        #pragma unroll
        for (int r = 0; r < 4; ++r) {
            int c = mt * 16 + fq * 4 + r;
            float a0 = acc[0][mt][r] + bias[c];
            float a1 = acc[1][mt][r] + bias[c];
            if (VAR == 0) {
                a0 += fmaf(hc0, sw[c], sb[c]);
                a1 += fmaf(hc1, sw[c], sb[c]);
            }
            if (VAR == 2) { a0 += v0[r]; a1 += v1[r]; }
            a0 = siluf(a0); a1 = siluf(a1);
            if (VAR == 1) { r0v[r] = a0; r1v[r] = a1; }
            else {
                float m = fmaxf(a0, a1);
                if (VAR == 2) r0v[r] = m;
                else { u16 hh = f2bf(m); hs[r] = hh; ls[r] = f2bf(m - bf2f(hh)); }
            }
        }
        if (VAR == 0) {
            size_t ob = (((size_t)(b * 96 + ho)) * NT + t) * 32 + mt * 16 + fq * 4;
            ushort4 hv = { hs[0], hs[1], hs[2], hs[3] };
            ushort4 lv = { ls[0], ls[1], ls[2], ls[3] };
            *(ushort4*)(Oh + ob) = hv;
            *(ushort4*)(Ol + ob) = lv;
        } else if (VAR == 1) {
            #pragma unroll
            for (int pr = 0; pr < 2; ++pr) {
                size_t ob = (((size_t)(b * 96 + 2 * ho + pr)) * NT + t) * 32 + mt * 16 + fq * 4;
                u16 hh[4], ll[4];
                #pragma unroll
                for (int r = 0; r < 4; ++r) {
                    float m = pr ? r1v[r] : r0v[r];
                    hh[r] = f2bf(m); ll[r] = f2bf(m - bf2f(hh[r]));
                }
                ushort4 hv = { hh[0], hh[1], hh[2], hh[3] };
                ushort4 lv = { ll[0], ll[1], ll[2], ll[3] };
                *(ushort4*)(Oh + ob) = hv;
                *(ushort4*)(Ol + ob) = lv;
            }
        } else {
            #pragma unroll
            for (int r = 0; r < 4; ++r) {
                int c = mt * 16 + fq * 4 + r;
                RES[((size_t)b * NT + t) * DMODEL + c * 48 + ho] = r0v[r];
            }
        }
    }
}

// ---------------- rmsnorm over D_MODEL -> bf16 hi/lo planes ----------------
__global__ __launch_bounds__(256) void k_rmsnorm(const float* __restrict__ in,
    const float* __restrict__ w, u16* __restrict__ oh, u16* __restrict__ ol)
{
    int row = blockIdx.x;
    int tid = threadIdx.x;
    const float* p = in + (size_t)row * DMODEL;
    float v[6]; float ss = 0.f;
    #pragma unroll
    for (int j = 0; j < 6; ++j) { v[j] = p[tid + j * 256]; ss = fmaf(v[j], v[j], ss); }
    #pragma unroll
    for (int off = 1; off < 64; off <<= 1) ss += __shfl_xor(ss, off);
    __shared__ float red[4];
    int lane = tid & 63, wv = tid >> 6;
    if (lane == 0) red[wv] = ss;
    __syncthreads();
    float tot = red[0] + red[1] + red[2] + red[3];
    float sc = rsqrtf(tot * (1.0f / DMODEL) + 1e-5f);
    #pragma unroll
    for (int j = 0; j < 6; ++j) {
        int col = tid + j * 256;
        float xv = v[j] * sc * w[col];
        u16 h = f2bf(xv);
        oh[(size_t)row * DMODEL + col] = h;
        ol[(size_t)row * DMODEL + col] = f2bf(xv - bf2f(h));
    }
}

// ---------------- split fp32 -> bf16 hi/lo (n divisible by 4) ----------------
__global__ __launch_bounds__(256) void k_split(const float* __restrict__ src,
    u16* __restrict__ dh, u16* __restrict__ dl, int n4)
{
    int idx = blockIdx.x * 256 + threadIdx.x;
    if (idx >= n4) return;
    float4 v = ((const float4*)src)[idx];
    u16 h0 = f2bf(v.x), h1 = f2bf(v.y), h2 = f2bf(v.z), h3 = f2bf(v.w);
    u16 l0 = f2bf(v.x - bf2f(h0)), l1 = f2bf(v.y - bf2f(h1));
    u16 l2 = f2bf(v.z - bf2f(h2)), l3 = f2bf(v.w - bf2f(h3));
    uint2 hv = { (u32)h0 | ((u32)h1 << 16), (u32)h2 | ((u32)h3 << 16) };
    uint2 lv = { (u32)l0 | ((u32)l1 << 16), (u32)l2 | ((u32)l3 << 16) };
    ((uint2*)dh)[idx] = hv;
    ((uint2*)dl)[idx] = lv;
}

// ---------------- fused per-layer weight split: xproj (vec4) + dt_w pad ----------------
__global__ __launch_bounds__(256) void k_wsplit2(
    const float* __restrict__ xpw, u16* __restrict__ xh, u16* __restrict__ xl,
    const float* __restrict__ dtw, u16* __restrict__ dh, u16* __restrict__ dl)
{
    int idx = blockIdx.x * 256 + threadIdx.x;
    if (idx < 98304) {
        float4 v = ((const float4*)xpw)[idx];
        u16 h0 = f2bf(v.x), h1 = f2bf(v.y), h2 = f2bf(v.z), h3 = f2bf(v.w);
        u16 l0 = f2bf(v.x - bf2f(h0)), l1 = f2bf(v.y - bf2f(h1));
        u16 l2 = f2bf(v.z - bf2f(h2)), l3 = f2bf(v.w - bf2f(h3));
        uint2 hv = { (u32)h0 | ((u32)h1 << 16), (u32)h2 | ((u32)h3 << 16) };
        uint2 lv = { (u32)l0 | ((u32)l1 << 16), (u32)l2 | ((u32)l3 << 16) };
        ((uint2*)xh)[idx] = hv;
        ((uint2*)xl)[idx] = lv;
        return;
    }
    int j = idx - 98304;
    if (j >= DINNER * 128) return;
    int col = j & 127, row = j >> 7;
    float v = (col < DTRANK) ? dtw[(size_t)row * DTRANK + col] : 0.f;
    u16 h = f2bf(v);
    dh[j] = h;
    dl[j] = f2bf(v - bf2f(h));
}

// ---------------- 128x128 MFMA GEMM (BK=64) for dt / x_proj ----------------
template<int EPI>
__global__ __launch_bounds__(256) void k_gemm_mfma(
    const u16* __restrict__ Ahi, const u16* __restrict__ Alo, int lda,
    const u16* __restrict__ Bhi, const u16* __restrict__ Blo, int ldb,
    float* __restrict__ C, int ldc, int Ktot,
    const float* __restrict__ bias, size_t zStride)
{
    __shared__ __align__(16) u16 lds[4][8192];
    const int tid = threadIdx.x;
    const int m0 = blockIdx.y * 128, n0 = blockIdx.x * 128;
    const int kPer = Ktot / gridDim.z;
    const int kBase = blockIdx.z * kPer;
    const int wid = tid >> 6, lane = tid & 63;
    const int wr = wid >> 1, wc = wid & 1;
    const int fr = lane & 15, fq = lane >> 4;
    const int srow  = tid >> 3;
    const int sslot = (tid & 7) ^ ((tid >> 3) & 7);

    f32x4 acc[4][4];
    #pragma unroll
    for (int mi = 0; mi < 4; ++mi)
        #pragma unroll
        for (int ni = 0; ni < 4; ++ni) acc[mi][ni] = (f32x4){0.f, 0.f, 0.f, 0.f};

    for (int k0 = kBase; k0 < kBase + kPer; k0 += 64) {
        #pragma unroll
        for (int i = 0; i < 4; ++i) {
            int row = i * 32 + srow;
            size_t offA = (size_t)(m0 + row) * lda + k0 + sslot * 8;
            size_t offB = (size_t)(n0 + row) * ldb + k0 + sslot * 8;
            u16* lb = &lds[0][0] + i * 2048 + (wid << 9);
            GLD(Ahi + offA, lb);
            GLD(Alo + offA, lb + 8192);
            GLD(Bhi + offB, lb + 16384);
            GLD(Blo + offB, lb + 24576);
        }
        __syncthreads();
        #pragma unroll
        for (int h = 0; h < 2; ++h) {
            bf16x8 ah[4], al[4], bh[4], bl[4];
            #pragma unroll
            for (int mi = 0; mi < 4; ++mi) {
                int row = wr * 64 + mi * 16 + fr;
                int sl  = (h * 4 + fq) ^ (row & 7);
                const u16* p = &lds[0][row * 64 + sl * 8];
                ah[mi] = *(const bf16x8*)p;
                al[mi] = *(const bf16x8*)(p + 8192);
            }
            #pragma unroll
            for (int ni = 0; ni < 4; ++ni) {
                int row = wc * 64 + ni * 16 + fr;
                int sl  = (h * 4 + fq) ^ (row & 7);
                const u16* p = &lds[2][row * 64 + sl * 8];
                bh[ni] = *(const bf16x8*)p;
                bl[ni] = *(const bf16x8*)(p + 8192);
            }
            #pragma unroll
            for (int mi = 0; mi < 4; ++mi)
                #pragma unroll
                for (int ni = 0; ni < 4; ++ni) {
                    acc[mi][ni] = __builtin_amdgcn_mfma_f32_16x16x32_bf16(ah[mi], bh[ni], acc[mi][ni], 0, 0, 0);
                    acc[mi][ni] = __builtin_amdgcn_mfma_f32_16x16x32_bf16(ah[mi], bl[ni], acc[mi][ni], 0, 0, 0);
                    acc[mi][ni] = __builtin_amdgcn_mfma_f32_16x16x32_bf16(al[mi], bh[ni], acc[mi][ni], 0, 0, 0);
                }
        }
        __syncthreads();
    }

    float* Cz = C + (EPI == 0 ? (size_t)blockIdx.z * zStride : (size_t)0);
    #pragma unroll
    for (int mi = 0; mi < 4; ++mi)
        #pragma unroll
        for (int ni = 0; ni < 4; ++ni) {
            int gr = m0 + wr * 64 + mi * 16 + fq * 4;
            int gc = n0 + wc * 64 + ni * 16 + fr;
            float* cp = Cz + (size_t)gr * ldc + gc;
            #pragma unroll
            for (int r = 0; r < 4; ++r) {
                float v = acc[mi][ni][r];
                if (EPI == 1) v = softplusf(v + bias[gc]);
                if (EPI == 2) v += cp[(size_t)r * ldc];
                cp[(size_t)r * ldc] = v;
            }
        }
}

// ---------------- 256xBN deep-phased MFMA GEMM (BK=32, 8 waves, free-run) ----------------
// Packed LDS per K-tile: [Ahi(256*64B) | Alo(256*64B) | Bhi(BN*64B) | Blo(BN*64B)],
// staged in 8KB units (512 thr x 16B); per-thread source computes plane/row/slot
// with the row-XOR swizzle; per-wave linear dest. BN=256 packs identically to the
// previous kernel; BN=192 gives grid 8x32 = 256 blocks (full CU round) for out_proj.
template<int EPI, int BN>
__global__ __launch_bounds__(512, 2) void k_gemm256(
    const u16* __restrict__ Ahi, const u16* __restrict__ Alo, int lda,
    const u16* __restrict__ Bhi, const u16* __restrict__ Blo, int ldb,
    float* __restrict__ C, int ldc, int Ktot)
{
    constexpr int BM = 256;
    constexpr int TILE = (2 * BM + 2 * BN) * 64;       // bytes per K-tile
    constexpr int NUNITS = TILE / 8192;
    constexpr int NI = BN / 64;                        // ni tiles per wave
    __shared__ __align__(16) u16 lds[2 * TILE / 2];
    const int tid = threadIdx.x;
    const int m0 = blockIdx.y * BM, n0 = blockIdx.x * BN;
    const int wid = tid >> 6, lane = tid & 63;
    const int wr = wid >> 2, wc = wid & 3;             // 2 x 4 waves
    const int fr = lane & 15, fq = lane >> 4;
    const int nK = Ktot / 32;

    auto STAGE = [&](int buf, int k0, int u) {
        int goff = u * 8192 + tid * 16;                // byte in packed tile
        int plane, rb;
        if (goff < BM * 64)                 { plane = 0; rb = goff; }
        else if (goff < 2 * BM * 64)        { plane = 1; rb = goff - BM * 64; }
        else if (goff < 2 * BM * 64 + BN * 64) { plane = 2; rb = goff - 2 * BM * 64; }
        else                                { plane = 3; rb = goff - 2 * BM * 64 - BN * 64; }
        int row  = rb >> 6;
        int slot = (rb >> 4) & 3;
        int ss   = slot ^ ((row >> 1) & 3);
        const u16* gp;
        if (plane == 0)      gp = Ahi + (size_t)(m0 + row) * lda + k0 + ss * 8;
        else if (plane == 1) gp = Alo + (size_t)(m0 + row) * lda + k0 + ss * 8;
        else if (plane == 2) gp = Bhi + (size_t)(n0 + row) * ldb + k0 + ss * 8;
        else                 gp = Blo + (size_t)(n0 + row) * ldb + k0 + ss * 8;
        u16* ldst = lds + ((size_t)buf * TILE + (size_t)u * 8192 + (size_t)wid * 1024) / 2;
        GLD(gp, ldst);
    };

    f32x4 acc[8][NI];
    #pragma unroll
    for (int mi = 0; mi < 8; ++mi)
        #pragma unroll
        for (int ni = 0; ni < NI; ++ni) acc[mi][ni] = (f32x4){0.f, 0.f, 0.f, 0.f};

    #pragma unroll
    for (int u = 0; u < NUNITS; ++u) STAGE(0, 0, u);

    for (int kt = 0; kt < nK; ++kt) {
        const int cur = kt & 1;
        __syncthreads();
        const int k1 = (kt + 1) * 32;
        const bool pf = (kt + 1 < nK);
        bf16x8 bh[NI], bl[NI];
        #pragma unroll
        for (int ni = 0; ni < NI; ++ni) {
            int row = wc * (BN / 4) + ni * 16 + fr;
            int sl  = fq ^ ((row >> 1) & 3);
            const u16* p = lds + ((size_t)cur * TILE + 2 * BM * 64 + (size_t)row * 64 + (size_t)sl * 16) / 2;
            bh[ni] = *(const bf16x8*)p;
            bl[ni] = *(const bf16x8*)(p + BN * 32);
        }
        #pragma unroll
        for (int q = 0; q < 4; ++q) {
            if (pf) {
                #pragma unroll
                for (int u = (q * NUNITS) / 4; u < ((q + 1) * NUNITS) / 4; ++u)
                    STAGE(cur ^ 1, k1, u);
            }
            bf16x8 ah[2], al[2];
            #pragma unroll
            for (int j = 0; j < 2; ++j) {
                int row = wr * 128 + (2 * q + j) * 16 + fr;
                int sl  = fq ^ ((row >> 1) & 3);
                const u16* p = lds + ((size_t)cur * TILE + (size_t)row * 64 + (size_t)sl * 16) / 2;
                ah[j] = *(const bf16x8*)p;
                al[j] = *(const bf16x8*)(p + BM * 32);
            }
            __builtin_amdgcn_s_setprio(1);
            #pragma unroll
            for (int j = 0; j < 2; ++j)
                #pragma unroll
                for (int ni = 0; ni < NI; ++ni) {
                    acc[2 * q + j][ni] = __builtin_amdgcn_mfma_f32_16x16x32_bf16(ah[j], bh[ni], acc[2 * q + j][ni], 0, 0, 0);
                    acc[2 * q + j][ni] = __builtin_amdgcn_mfma_f32_16x16x32_bf16(ah[j], bl[ni], acc[2 * q + j][ni], 0, 0, 0);
                    acc[2 * q + j][ni] = __builtin_amdgcn_mfma_f32_16x16x32_bf16(al[j], bh[ni], acc[2 * q + j][ni], 0, 0, 0);
                }
            __builtin_amdgcn_s_setprio(0);
        }
    }

    #pragma unroll
    for (int mi = 0; mi < 8; ++mi)
        #pragma unroll
        for (int ni = 0; ni < NI; ++ni) {
            int gr = m0 + wr * 128 + mi * 16 + fq * 4;
            int gc = n0 + wc * (BN / 4) + ni * 16 + fr;
            float* cp = C + (size_t)gr * ldc + gc;
            #pragma unroll
            for (int r = 0; r < 4; ++r) {
                float v = acc[mi][ni][r];
                if (EPI == 2) v += cp[(size_t)r * ldc];
                cp[(size_t)r * ldc] = v;
            }
        }
}

// ---------------- depthwise causal conv1d(k=4)+bias+silu -> u hi/lo ----------------
__global__ __launch_bounds__(256) void k_conv1d(
    const float* __restrict__ xz, const float* __restrict__ w,
    const float* __restrict__ bias, u16* __restrict__ uh, u16* __restrict__ ul)
{
    constexpr int CT = 16;
    const int d  = (blockIdx.x * 256 + threadIdx.x) * 2;
    const int t0 = blockIdx.y * CT;
    const int b  = blockIdx.z;
    float4 w0 = *(const float4*)(w + (size_t)d * 4);
    float4 w1 = *(const float4*)(w + (size_t)(d + 1) * 4);
    float2 bb = *(const float2*)(bias + d);
    const float* xp = xz + ((size_t)b * NT + t0) * (2 * DINNER) + d;
    float2 a0 = {0.f, 0.f}, a1 = {0.f, 0.f}, a2 = {0.f, 0.f};
    if (t0 > 0) {
        a0 = *(const float2*)(xp - 3 * 2 * DINNER);
        a1 = *(const float2*)(xp - 2 * 2 * DINNER);
        a2 = *(const float2*)(xp - 1 * 2 * DINNER);
    }
    u32* uhp = (u32*)(uh + ((size_t)b * NT + t0) * DINNER + d);
    u32* ulp = (u32*)(ul + ((size_t)b * NT + t0) * DINNER + d);
    #pragma unroll
    for (int t = 0; t < CT; ++t) {
        float2 a3 = *(const float2*)(xp + (size_t)t * 2 * DINNER);
        float o0 = siluf(bb.x + a0.x * w0.x + a1.x * w0.y + a2.x * w0.z + a3.x * w0.w);
        float o1 = siluf(bb.y + a0.y * w1.x + a1.y * w1.y + a2.y * w1.z + a3.y * w1.w);
        u16 h0 = f2bf(o0), h1 = f2bf(o1);
        u16 l0 = f2bf(o0 - bf2f(h0)), l1 = f2bf(o1 - bf2f(h1));
        uhp[(size_t)t * (DINNER / 2)] = (u32)h0 | ((u32)h1 << 16);
        ulp[(size_t)t * (DINNER / 2)] = (u32)l0 | ((u32)l1 << 16);
        a0 = a1; a1 = a2; a2 = a3;
    }
}

// ---------------- reduce 4 split-K slabs of x_proj + split to hi/lo ----------------
__global__ __launch_bounds__(256) void k_reduce_split(const float* __restrict__ part,
    float* __restrict__ out, u16* __restrict__ dh, u16* __restrict__ dl)
{
    int idx = blockIdx.x * 256 + threadIdx.x;
    if (idx >= MROWS * 128) return;
    float s = part[idx] + part[(size_t)1 * MROWS * 128 + idx]
            + part[(size_t)2 * MROWS * 128 + idx] + part[(size_t)3 * MROWS * 128 + idx];
    out[idx] = s;
    u16 h = f2bf(s);
    dh[idx] = h;
    dl[idx] = f2bf(s - bf2f(h));
}

// ---------------- scan pass 1: lane-per-d local chunk scan (all regs) ----------------
__global__ __launch_bounds__(256) void k_scan_p1(
    const float* __restrict__ xz, const u16* __restrict__ uh, const u16* __restrict__ ul,
    const float* __restrict__ xdbl, const float* __restrict__ A_log,
    float* __restrict__ HP, float* __restrict__ SS)
{
    const int d = blockIdx.x * 256 + threadIdx.x;
    const int c = blockIdx.y, b = blockIdx.z;
    const float L2E = 1.44269504088896340736f;
    f32x4 al0 = *(const f32x4*)(A_log + (size_t)d * DSTATE + 0);
    f32x4 al1 = *(const f32x4*)(A_log + (size_t)d * DSTATE + 4);
    f32x4 al2 = *(const f32x4*)(A_log + (size_t)d * DSTATE + 8);
    f32x4 al3 = *(const f32x4*)(A_log + (size_t)d * DSTATE + 12);
    f32x4 aa0, aa1, aa2, aa3;
    #pragma unroll
    for (int j = 0; j < 4; ++j) {
        aa0[j] = -__expf(al0[j]) * L2E;
        aa1[j] = -__expf(al1[j]) * L2E;
        aa2[j] = -__expf(al2[j]) * L2E;
        aa3[j] = -__expf(al3[j]) * L2E;
    }
    const int t0 = c * CHKT;
    const float* dP = xz + ((size_t)b * NT + t0) * (2 * DINNER) + d;
    const u16* uhP = uh + ((size_t)b * NT + t0) * DINNER + d;
    const u16* ulP = ul + ((size_t)b * NT + t0) * DINNER + d;
    const float* bP = xdbl + ((size_t)b * NT + t0) * 128 + DTRANK;
    f32x4 h0 = {0.f,0.f,0.f,0.f}, h1 = h0, h2 = h0, h3 = h0;
    float S = 0.f;
    float dlt = dP[0];
    float uu = bf2f(uhP[0]) + bf2f(ulP[0]);
    for (int t = 0; t < CHKT; ++t) {
        float dlt_n = 0.f, uu_n = 0.f;
        if (t + 1 < CHKT) {
            dlt_n = dP[2 * DINNER];
            uu_n = bf2f(uhP[DINNER]) + bf2f(ulP[DINNER]);
        }
        f32x4 B0 = *(const f32x4*)(bP + 0);
        f32x4 B1 = *(const f32x4*)(bP + 4);
        f32x4 B2 = *(const f32x4*)(bP + 8);
        f32x4 B3 = *(const f32x4*)(bP + 12);
        float du = dlt * uu;
        S += dlt;
        h0 = exp2v(dlt * aa0) * h0 + du * B0;
        h1 = exp2v(dlt * aa1) * h1 + du * B1;
        h2 = exp2v(dlt * aa2) * h2 + du * B2;
        h3 = exp2v(dlt * aa3) * h3 + du * B3;
        dP += 2 * DINNER; uhP += DINNER; ulP += DINNER; bP += 128;
        dlt = dlt_n; uu = uu_n;
    }
    size_t a = (((size_t)(b * NCHK + c) * DINNER) + d) * DSTATE;
    *(f32x4*)(HP + a + 0)  = h0;
    *(f32x4*)(HP + a + 4)  = h1;
    *(f32x4*)(HP + a + 8)  = h2;
    *(f32x4*)(HP + a + 12) = h3;
    SS[(size_t)(b * NCHK + c) * DINNER + d] = S;
}

// ---------------- scan pass 2: chunk-prefix; HP becomes h_init per chunk ----------------
__global__ __launch_bounds__(256) void k_scan_p2(float* __restrict__ HP,
    const float* __restrict__ SS, const float* __restrict__ A_log)
{
    int idx = blockIdx.x * 256 + threadIdx.x;
    if (idx >= NB * DINNER * DSTATE) return;
    int s = idx & (DSTATE - 1);
    int d = (idx >> 4) % DINNER;
    int b = idx / (DINNER * DSTATE);
    const float L2E = 1.44269504088896340736f;
    float aa = -__expf(A_log[d * DSTATE + s]) * L2E;
    float h = 0.f;
    #pragma unroll
    for (int c = 0; c < NCHK; ++c) {
        size_t a = (((size_t)(b * NCHK + c) * DINNER) + d) * DSTATE + s;
        float hc = HP[a];
        float P = exp2f(aa * SS[(size_t)(b * NCHK + c) * DINNER + d]);
        HP[a] = h;
        h = fmaf(P, h, hc);
    }
}

// ---------------- scan pass 3: lane-per-d chunk scan with h_init (all regs) ----------------
__global__ __launch_bounds__(256) void k_scan_p3(
    const float* __restrict__ xz,
    u16* uh, u16* ul,
    const float* __restrict__ xdbl,
    const float* __restrict__ A_log, const float* __restrict__ Dp,
    const float* __restrict__ HP)
{
    const int d = blockIdx.x * 256 + threadIdx.x;
    const int c = blockIdx.y, b = blockIdx.z;
    const float L2E = 1.44269504088896340736f;
    f32x4 al0 = *(const f32x4*)(A_log + (size_t)d * DSTATE + 0);
    f32x4 al1 = *(const f32x4*)(A_log + (size_t)d * DSTATE + 4);
    f32x4 al2 = *(const f32x4*)(A_log + (size_t)d * DSTATE + 8);
    f32x4 al3 = *(const f32x4*)(A_log + (size_t)d * DSTATE + 12);
    f32x4 aa0, aa1, aa2, aa3;
    #pragma unroll
    for (int j = 0; j < 4; ++j) {
        aa0[j] = -__expf(al0[j]) * L2E;
        aa1[j] = -__expf(al1[j]) * L2E;
        aa2[j] = -__expf(al2[j]) * L2E;
        aa3[j] = -__expf(al3[j]) * L2E;
    }
    const float dp = Dp[d];
    const int t0 = c * CHKT;
    const float* dP = xz + ((size_t)b * NT + t0) * (2 * DINNER) + d;
    const float* zP = dP + DINNER;
    const u16* uhP = uh + ((size_t)b * NT + t0) * DINNER + d;
    const u16* ulP = ul + ((size_t)b * NT + t0) * DINNER + d;
    u16* yhP = (u16*)uhP;
    u16* ylP = (u16*)ulP;
    const float* bP = xdbl + ((size_t)b * NT + t0) * 128 + DTRANK;
    size_t ha = (((size_t)(b * NCHK + c) * DINNER) + d) * DSTATE;
    f32x4 h0 = *(const f32x4*)(HP + ha + 0);
    f32x4 h1 = *(const f32x4*)(HP + ha + 4);
    f32x4 h2 = *(const f32x4*)(HP + ha + 8);
    f32x4 h3 = *(const f32x4*)(HP + ha + 12);
    float dlt = dP[0], zz = zP[0];
    float uu = bf2f(uhP[0]) + bf2f(ulP[0]);
    for (int t = 0; t < CHKT; ++t) {
        float dlt_n = 0.f, uu_n = 0.f, zz_n = 0.f;
        if (t + 1 < CHKT) {
            dlt_n = dP[2 * DINNER]; zz_n = zP[2 * DINNER];
            uu_n = bf2f(uhP[DINNER]) + bf2f(ulP[DINNER]);
        }
        f32x4 B0 = *(const f32x4*)(bP + 0);
        f32x4 B1 = *(const f32x4*)(bP + 4);
        f32x4 B2 = *(const f32x4*)(bP + 8);
        f32x4 B3 = *(const f32x4*)(bP + 12);
        f32x4 C0 = *(const f32x4*)(bP + DSTATE + 0);
        f32x4 C1 = *(const f32x4*)(bP + DSTATE + 4);
        f32x4 C2 = *(const f32x4*)(bP + DSTATE + 8);
        f32x4 C3 = *(const f32x4*)(bP + DSTATE + 12);
        float du = dlt * uu;
        h0 = exp2v(dlt * aa0) * h0 + du * B0;
        h1 = exp2v(dlt * aa1) * h1 + du * B1;
        h2 = exp2v(dlt * aa2) * h2 + du * B2;
        h3 = exp2v(dlt * aa3) * h3 + du * B3;
        f32x4 pv = h0 * C0 + h1 * C1 + h2 * C2 + h3 * C3;
        float p = (pv[0] + pv[1]) + (pv[2] + pv[3]);
        float yv = (p + uu * dp) * siluf(zz);
        u16 hh = f2bf(yv);
        yhP[0] = hh;
        ylP[0] = f2bf(yv - bf2f(hh));
        dP += 2 * DINNER; zP += 2 * DINNER;
        uhP += DINNER; ulP += DINNER; yhP += DINNER; ylP += DINNER;
        bP += 128;
        dlt = dlt_n; zz = zz_n; uu = uu_n;
    }
}

// ---------------- final fc + silu + transpose to (B,5,T) ----------------
__global__ __launch_bounds__(256) void k_fc(const float* __restrict__ hR,
    const float* __restrict__ w, const float* __restrict__ bias,
    float* __restrict__ out)
{
    int row = blockIdx.x;
    int tid = threadIdx.x;
    const float* p = hR + (size_t)row * DMODEL;
    float acc[NCLASS] = {0.f, 0.f, 0.f, 0.f, 0.f};
    #pragma unroll
    for (int j = 0; j < 6; ++j) {
        int col = tid + j * 256;
        float v = p[col];
        #pragma unroll
        for (int c = 0; c < NCLASS; ++c)
            acc[c] = fmaf(v, w[c * DMODEL + col], acc[c]);
    }
    #pragma unroll
    for (int c = 0; c < NCLASS; ++c)
        #pragma unroll
        for (int off = 1; off < 64; off <<= 1)
            acc[c] += __shfl_xor(acc[c], off);
    __shared__ float red[4][NCLASS];
    int lane = tid & 63, wv = tid >> 6;
    if (lane == 0)
        for (int c = 0; c < NCLASS; ++c) red[wv][c] = acc[c];
    __syncthreads();
    if (tid < NCLASS) {
        float s = red[0][tid] + red[1][tid] + red[2][tid] + red[3][tid] + bias[tid];
        int b = row >> 10, t = row & (NT - 1);
        out[((size_t)b * NCLASS + tid) * NT + t] = siluf(s);
    }
}

extern "C" void kernel_launch(void* const* d_in, const int* in_sizes, int n_in,
                              void* d_out, int out_size, void* d_ws, size_t ws_size,
                              hipStream_t stream)
{
    const float* x      = (const float*)d_in[0];
    const float* c1a_w  = (const float*)d_in[1];
    const float* c1a_b  = (const float*)d_in[2];
    const float* c1b_w  = (const float*)d_in[3];
    const float* c1b_b  = (const float*)d_in[4];
    const float* c1s_w  = (const float*)d_in[5];
    const float* c1s_b  = (const float*)d_in[6];
    const float* c2a_w  = (const float*)d_in[7];
    const float* c2a_b  = (const float*)d_in[8];
    const float* c2b_w  = (const float*)d_in[9];
    const float* c2b_b  = (const float*)d_in[10];
    const float* norm_w = (const float*)d_in[11];
    const float* in_w   = (const float*)d_in[12];
    const float* conv_w = (const float*)d_in[13];
    const float* conv_b = (const float*)d_in[14];
    const float* xproj_w= (const float*)d_in[15];
    const float* dt_w   = (const float*)d_in[16];
    const float* dt_b   = (const float*)d_in[17];
    const float* A_log  = (const float*)d_in[18];
    const float* Dp     = (const float*)d_in[19];
    const float* out_w  = (const float*)d_in[20];
    const float* fc_w   = (const float*)d_in[21];
    const float* fc_b   = (const float*)d_in[22];
    float* outp = (float*)d_out;
    (void)in_sizes; (void)n_in; (void)out_size; (void)ws_size;

    char* base = (char*)d_ws;
    size_t off = 0;
    auto takeB = [&](size_t bytes) { void* p = base + off; off = (off + bytes + 255) & ~(size_t)255; return p; };
    float* HCAT = (float*)takeB((size_t)NB * NDIM * NT * 4);
    float* XZ   = (float*)takeB((size_t)MROWS * 2 * DINNER * 4);
    float* RES  = (float*)takeB((size_t)MROWS * DMODEL * 4);
    u16*   XNh  = (u16*)takeB((size_t)MROWS * DMODEL * 2);
    u16*   XNl  = (u16*)takeB((size_t)MROWS * DMODEL * 2);
    u16*   Uh   = (u16*)takeB((size_t)MROWS * DINNER * 2);
    u16*   Ul   = (u16*)takeB((size_t)MROWS * DINNER * 2);
    float* XDBL = (float*)takeB((size_t)MROWS * 128 * 4);
    float* XPART= (float*)takeB((size_t)4 * MROWS * 128 * 4);
    u16*   XDh  = (u16*)takeB((size_t)MROWS * 128 * 2);
    u16*   XDl  = (u16*)takeB((size_t)MROWS * 128 * 2);
    u16*   Wh   = (u16*)takeB((size_t)9437184 * 2);
    u16*   Wl   = (u16*)takeB((size_t)9437184 * 2);
    u16*   DTh  = (u16*)takeB((size_t)DINNER * 128 * 2);
    u16*   DTl  = (u16*)takeB((size_t)DINNER * 128 * 2);
    float* HP   = (float*)takeB((size_t)NB * NCHK * DINNER * DSTATE * 4);
    float* SS   = (float*)takeB((size_t)NB * NCHK * DINNER * 4);
    u16*   CW1h = (u16*)takeB(18432);
    u16*   CW1l = (u16*)takeB(18432);
    u16*   CW2h = (u16*)takeB(18432);
    u16*   CW2l = (u16*)takeB(18432);
    u16*   CW3h = (u16*)takeB(18432);
    u16*   CW3l = (u16*)takeB(18432);
    u16*   ZPAD = (u16*)takeB(256);

    u16* T1h = (u16*)XZ;
    u16* T1l = T1h + (size_t)NB * NDIM * NT * 32;
    u16* T3h = (u16*)XZ;
    u16* T3l = T3h + (size_t)NB * NDIM * NT * 32;
    u16* P1h = Uh;
    u16* P1l = Ul;

    const int n1 = NB * NDIM * NT;
    k_prep  <<<(n1 + 255) / 256, 256, 0, stream>>>(x, HCAT, ZPAD);
    k_wconv3<<<dim3(36, 3), 256, 0, stream>>>(c1b_w, CW1h, CW1l,
                                              c2a_w, CW2h, CW2l,
                                              c2b_w, CW3h, CW3l);
    k_conv1a<<<(n1 + 255) / 256, 256, 0, stream>>>(HCAT, c1a_w, c1a_b, T1h, T1l);
    k_convmfma<0><<<dim3(16, 96, NB), 256, 0, stream>>>(
        T1h, T1l, CW1h, CW1l, HCAT, c1s_w, c1s_b, nullptr, nullptr,
        c1b_b, P1h, P1l, nullptr, ZPAD);
    k_convmfma<1><<<dim3(16, 48, NB), 256, 0, stream>>>(
        P1h, P1l, CW2h, CW2l, nullptr, nullptr, nullptr, nullptr, nullptr,
        c2a_b, T3h, T3l, nullptr, ZPAD);
    k_convmfma<2><<<dim3(16, 48, NB), 256, 0, stream>>>(
        T3h, T3l, CW3h, CW3l, nullptr, nullptr, nullptr, P1h, P1l,
        c2b_b, nullptr, nullptr, RES, ZPAD);

    for (int l = 0; l < NLAYER; ++l) {
        k_rmsnorm<<<MROWS, 256, 0, stream>>>(RES, norm_w + (size_t)l * DMODEL, XNh, XNl);
        k_split<<<(9437184 / 4 + 255) / 256, 256, 0, stream>>>(
            in_w + (size_t)l * 2 * DINNER * DMODEL, Wh, Wl, 9437184 / 4);
        k_gemm256<0, 256><<<dim3(2 * DINNER / 256, MROWS / 256), 512, 0, stream>>>(
            XNh, XNl, DMODEL, Wh, Wl, DMODEL, XZ, 2 * DINNER, DMODEL);
        k_conv1d<<<dim3(DINNER / 512, NT / 16, NB), 256, 0, stream>>>(
            XZ, conv_w + (size_t)l * DINNER * 4, conv_b + (size_t)l * DINNER, Uh, Ul);
        k_wsplit2<<<(98304 + DINNER * 128 + 255) / 256, 256, 0, stream>>>(
            xproj_w + (size_t)l * 128 * DINNER, Wh, Wl,
            dt_w + (size_t)l * DINNER * DTRANK, DTh, DTl);
        k_gemm_mfma<0><<<dim3(1, MROWS / 128, 4), 256, 0, stream>>>(
            Uh, Ul, DINNER, Wh, Wl, DINNER, XPART, 128, DINNER, nullptr, (size_t)MROWS * 128);
        k_reduce_split<<<(MROWS * 128 + 255) / 256, 256, 0, stream>>>(XPART, XDBL, XDh, XDl);
        k_gemm_mfma<1><<<dim3(DINNER / 128, MROWS / 128, 1), 256, 0, stream>>>(
            XDh, XDl, 128, DTh, DTl, 128, XZ, 2 * DINNER, 128,
            dt_b + (size_t)l * DINNER, 0);
        k_scan_p1<<<dim3(DINNER / 256, NCHK, NB), 256, 0, stream>>>(
            XZ, Uh, Ul, XDBL, A_log + (size_t)l * DINNER * DSTATE, HP, SS);
        k_scan_p2<<<(NB * DINNER * DSTATE + 255) / 256, 256, 0, stream>>>(
            HP, SS, A_log + (size_t)l * DINNER * DSTATE);
        k_scan_p3<<<dim3(DINNER / 256, NCHK, NB), 256, 0, stream>>>(
            XZ, Uh, Ul, XDBL, A_log + (size_t)l * DINNER * DSTATE,
            Dp + (size_t)l * DINNER, HP);
        k_split<<<(4718592 / 4 + 255) / 256, 256, 0, stream>>>(
            out_w + (size_t)l * DMODEL * DINNER, Wh, Wl, 4718592 / 4);
        k_gemm256<2, 192><<<dim3(DMODEL / 192, MROWS / 256), 512, 0, stream>>>(
            Uh, Ul, DINNER, Wh, Wl, DINNER, RES, DMODEL, DINNER);
    }
    k_fc<<<MROWS, 256, 0, stream>>>(RES, fc_w, fc_b, outp);
}

// Round 15
// 4581.217 us; speedup vs baseline: 1.0171x; 1.0171x over previous
//
#include <hip/hip_runtime.h>
#include <cstdint>
#include <cstddef>

#define DEV static __device__ __forceinline__

typedef unsigned short u16;
typedef unsigned int   u32;
typedef __bf16 bf16x8 __attribute__((ext_vector_type(8)));
typedef float  f32x4  __attribute__((ext_vector_type(4)));

namespace {
constexpr int NB     = 8;
constexpr int NT     = 1024;
constexpr int NMEL   = 96;
constexpr int NDIM   = 192;
constexpr int NCH    = 32;
constexpr int DMODEL = 1536;
constexpr int DINNER = 3072;
constexpr int DSTATE = 16;
constexpr int DTRANK = 96;
constexpr int NLAYER = 4;
constexpr int NCLASS = 5;
constexpr int MROWS  = NB * NT;   // 8192
constexpr int NCHK   = 16;
constexpr int CHKT   = NT / NCHK; // 64
}

DEV float siluf(float x)    { return x / (1.0f + __expf(-x)); }
DEV float softplusf(float x){ return fmaxf(x, 0.0f) + log1pf(__expf(-fabsf(x))); }

DEV u16 f2bf(float f) {
    u32 u = __float_as_uint(f);
    u32 r = u + 0x7FFFu + ((u >> 16) & 1u);
    return (u16)(r >> 16);
}
DEV float bf2f(u16 h) { return __uint_as_float(((u32)h) << 16); }

DEV f32x4 exp2v(f32x4 x) {
    f32x4 r;
    r[0] = exp2f(x[0]); r[1] = exp2f(x[1]);
    r[2] = exp2f(x[2]); r[3] = exp2f(x[3]);
    return r;
}

#define GLD(gp, lp) __builtin_amdgcn_global_load_lds( \
    (const __attribute__((address_space(1))) u32*)(const void*)(gp), \
    (__attribute__((address_space(3))) u32*)(void*)(lp), 16, 0, 0)

// ---------------- prep: x -> hcat (B,192,T): [x ; relu(diff)]; also zero ZPAD ----------------
__global__ __launch_bounds__(256) void k_prep(const float* __restrict__ x,
                                              float* __restrict__ hcat,
                                              u16* __restrict__ zpad)
{
    if (blockIdx.x == 0 && threadIdx.x < 128) zpad[threadIdx.x] = 0;
    int idx = blockIdx.x * 256 + threadIdx.x;
    if (idx >= NB * NDIM * NT) return;
    int t = idx & (NT - 1);
    int m = (idx >> 10) % NDIM;
    int b = idx / (NDIM * NT);
    float v;
    if (m < NMEL) {
        v = x[((size_t)b * NMEL + m) * NT + t];
    } else {
        int mm = m - NMEL;
        v = 0.f;
        if (t > 0) {
            const float* p = x + ((size_t)b * NMEL + mm) * NT + t;
            v = fmaxf(p[0] - p[-1], 0.f);
        }
    }
    hcat[idx] = v;
}

// ---------------- conv weight prep x3: (32,32,3,3) -> [tap][cout][ci] hi/lo ----------------
__global__ __launch_bounds__(256) void k_wconv3(
    const float* __restrict__ w0, u16* __restrict__ dh0, u16* __restrict__ dl0,
    const float* __restrict__ w1, u16* __restrict__ dh1, u16* __restrict__ dl1,
    const float* __restrict__ w2, u16* __restrict__ dh2, u16* __restrict__ dl2)
{
    int idx = blockIdx.x * 256 + threadIdx.x;
    if (idx >= 9216) return;
    const float* w = (blockIdx.y == 0) ? w0 : (blockIdx.y == 1) ? w1 : w2;
    u16* dh = (blockIdx.y == 0) ? dh0 : (blockIdx.y == 1) ? dh1 : dh2;
    u16* dl = (blockIdx.y == 0) ? dl0 : (blockIdx.y == 1) ? dl1 : dl2;
    int ci = idx & 31, cout = (idx >> 5) & 31, tap = idx >> 10;
    float v = w[((size_t)cout * 32 + ci) * 9 + tap];
    u16 h = f2bf(v);
    dh[idx] = h;
    dl[idx] = f2bf(v - bf2f(h));
}

// ---------------- conv1a (1->32, 3x3) + silu -> NHWC bf16 hi/lo ----------------
__global__ __launch_bounds__(256) void k_conv1a(const float* __restrict__ hcat,
    const float* __restrict__ w, const float* __restrict__ bias,
    u16* __restrict__ oh, u16* __restrict__ ol)   // (B,192,T,32)
{
    int idx = blockIdx.x * 256 + threadIdx.x;
    if (idx >= NB * NDIM * NT) return;
    int t = idx & (NT - 1);
    int h = (idx >> 10) % NDIM;
    int b = idx / (NDIM * NT);
    float in[3][3];
    #pragma unroll
    for (int dh = 0; dh < 3; ++dh)
        #pragma unroll
        for (int dw = 0; dw < 3; ++dw) {
            int hh = h + dh - 1, tt = t + dw - 1;
            in[dh][dw] = (hh >= 0 && hh < NDIM && tt >= 0 && tt < NT)
                       ? hcat[((size_t)b * NDIM + hh) * NT + tt] : 0.f;
        }
    u16 hb[32], lb[32];
    #pragma unroll
    for (int c = 0; c < NCH; ++c) {
        float acc = bias[c];
        #pragma unroll
        for (int dh = 0; dh < 3; ++dh)
            #pragma unroll
            for (int dw = 0; dw < 3; ++dw)
                acc = fmaf(in[dh][dw], w[c * 9 + dh * 3 + dw], acc);
        float o = siluf(acc);
        u16 hh2 = f2bf(o);
        hb[c] = hh2;
        lb[c] = f2bf(o - bf2f(hh2));
    }
    size_t ob = (((size_t)b * NDIM + h) * NT + t) * 32;
    #pragma unroll
    for (int j = 0; j < 8; ++j) {
        ushort4 hv = { hb[j*4], hb[j*4+1], hb[j*4+2], hb[j*4+3] };
        ushort4 lv = { lb[j*4], lb[j*4+1], lb[j*4+2], lb[j*4+3] };
        *(ushort4*)(oh + ob + j * 4) = hv;
        *(ushort4*)(ol + ob + j * 4) = lv;
    }
}

// ---------------- MFMA implicit-GEMM conv 32->32 3x3 (NHWC bf16 hi/lo) ----------------
template<int VAR>
__global__ __launch_bounds__(256) void k_convmfma(
    const u16* __restrict__ Xh, const u16* __restrict__ Xl,
    const u16* __restrict__ CWh, const u16* __restrict__ CWl,
    const float* __restrict__ hcat, const float* __restrict__ sw, const float* __restrict__ sb,
    const u16* __restrict__ Sh, const u16* __restrict__ Sl,
    const float* __restrict__ bias,
    u16* __restrict__ Oh, u16* __restrict__ Ol,
    float* __restrict__ RES,
    const u16* __restrict__ zeropad)
{
    constexpr int HIN = (VAR == 0) ? 192 : 96;
    __shared__ __align__(16) u16 lds[2][8448];
    const int t0 = blockIdx.x * 64;
    const int ho = blockIdx.y;
    const int b  = blockIdx.z;
    const int tid = threadIdx.x;
    const int wid = tid >> 6, lane = tid & 63;
    const int r0 = 2 * ho - 1;

    for (int cb = wid * 64; cb < 2112; cb += 256) {
        int c = cb + lane;
        int plane = (c >= 1056) ? 1 : 0;
        int cc = c - plane * 1056;
        int row = cc / 264;
        int rc  = cc - row * 264;
        int pos = rc >> 2;
        int slot = rc & 3;
        int cib = slot ^ ((pos >> 1) & 3);
        int h = r0 + row;
        int t = t0 - 1 + pos;
        const u16* bp = plane ? Xl : Xh;
        const u16* src = (h >= 0 && h < HIN && t >= 0 && t < NT)
            ? bp + (((size_t)(b * HIN + h)) * NT + t) * 32 + cib * 8
            : zeropad;
        u16* ldst = &lds[0][0] + (size_t)cb * 8;
        GLD(src, ldst);
    }
    __syncthreads();

    const int fr = lane & 15, fq = lane >> 4;
    f32x4 acc[2][2];
    #pragma unroll
    for (int pr = 0; pr < 2; ++pr)
        #pragma unroll
        for (int mt = 0; mt < 2; ++mt) acc[pr][mt] = (f32x4){0.f, 0.f, 0.f, 0.f};

    #pragma unroll
    for (int dh = 0; dh < 3; ++dh) {
        #pragma unroll
        for (int dt = 0; dt < 3; ++dt) {
            int tap = dh * 3 + dt;
            bf16x8 wh[2], wl[2];
            #pragma unroll
            for (int mt = 0; mt < 2; ++mt) {
                size_t wo = ((size_t)tap * 32 + mt * 16 + fr) * 32 + fq * 8;
                wh[mt] = *(const bf16x8*)(CWh + wo);
                wl[mt] = *(const bf16x8*)(CWl + wo);
            }
            int p = (wid << 4) + fr + dt;
            int sl = fq ^ ((p >> 1) & 3);
            #pragma unroll
            for (int pr = 0; pr < 2; ++pr) {
                int rr = pr + dh;
                const u16* lp = &lds[0][0] + ((rr * 66 + p) * 4 + sl) * 8;
                bf16x8 xh = *(const bf16x8*)lp;
                bf16x8 xl = *(const bf16x8*)(lp + 8448);
                #pragma unroll
                for (int mt = 0; mt < 2; ++mt) {
                    acc[pr][mt] = __builtin_amdgcn_mfma_f32_16x16x32_bf16(wh[mt], xh, acc[pr][mt], 0, 0, 0);
                    acc[pr][mt] = __builtin_amdgcn_mfma_f32_16x16x32_bf16(wh[mt], xl, acc[pr][mt], 0, 0, 0);
                    acc[pr][mt] = __builtin_amdgcn_mfma_f32_16x16x32_bf16(wl[mt], xh, acc[pr][mt], 0, 0, 0);
                }
            }
        }
    }

    const int t = t0 + (wid << 4) + fr;
    float hc0 = 0.f, hc1 = 0.f;
    if (VAR == 0) {
        hc0 = hcat[((size_t)(b * NDIM + 2 * ho    )) * NT + t];
        hc1 = hcat[((size_t)(b * NDIM + 2 * ho + 1)) * NT + t];
    }
    #pragma unroll
    for (int mt = 0; mt < 2; ++mt) {
        float v0[4], v1[4];
        if (VAR == 2) {
            ushort4 s0h = *(const ushort4*)(Sh + (((size_t)(b * 96 + 2 * ho    )) * NT + t) * 32 + mt * 16 + fq * 4);
            ushort4 s0l = *(const ushort4*)(Sl + (((size_t)(b * 96 + 2 * ho    )) * NT + t) * 32 + mt * 16 + fq * 4);
            ushort4 s1h = *(const ushort4*)(Sh + (((size_t)(b * 96 + 2 * ho + 1)) * NT + t) * 32 + mt * 16 + fq * 4);
            ushort4 s1l = *(const ushort4*)(Sl + (((size_t)(b * 96 + 2 * ho + 1)) * NT + t) * 32 + mt * 16 + fq * 4);
            v0[0] = bf2f(s0h.x) + bf2f(s0l.x); v0[1] = bf2f(s0h.y) + bf2f(s0l.y);
            v0[2] = bf2f(s0h.z) + bf2f(s0l.z); v0[3] = bf2f(s0h.w) + bf2f(s0l.w);
            v1[0] = bf2f(s1h.x) + bf2f(s1l.x); v1[1] = bf2f(s1h.y) + bf2f(s1l.y);
            v1[2] = bf2f(s1h.z) + bf2f(s1l.z); v1[3] = bf2f(s1h.w) + bf2f(s1l.w);
        }
        u16 hs[4], ls[4];
        float r0v[4], r1v[4];
        #pragma unroll
        for (int r = 0; r < 4; ++r) {
            int c = mt * 16 + fq * 4 + r;
            float a0 = acc[0][mt][r] + bias[c];
            float a1 = acc[1][mt][r] + bias[c];
            if (VAR == 0) {
                a0 += fmaf(hc0, sw[c], sb[c]);
                a1 += fmaf(hc1, sw[c], sb[c]);
            }
            if (VAR == 2) { a0 += v0[r]; a1 += v1[r]; }
            a0 = siluf(a0); a1 = siluf(a1);
            if (VAR == 1) { r0v[r] = a0; r1v[r] = a1; }
            else {
                float m = fmaxf(a0, a1);
                if (VAR == 2) r0v[r] = m;
                else { u16 hh = f2bf(m); hs[r] = hh; ls[r] = f2bf(m - bf2f(hh)); }
            }
        }
        if (VAR == 0) {
            size_t ob = (((size_t)(b * 96 + ho)) * NT + t) * 32 + mt * 16 + fq * 4;
            ushort4 hv = { hs[0], hs[1], hs[2], hs[3] };
            ushort4 lv = { ls[0], ls[1], ls[2], ls[3] };
            *(ushort4*)(Oh + ob) = hv;
            *(ushort4*)(Ol + ob) = lv;
        } else if (VAR == 1) {
            #pragma unroll
            for (int pr = 0; pr < 2; ++pr) {
                size_t ob = (((size_t)(b * 96 + 2 * ho + pr)) * NT + t) * 32 + mt * 16 + fq * 4;
                u16 hh[4], ll[4];
                #pragma unroll
                for (int r = 0; r < 4; ++r) {
                    float m = pr ? r1v[r] : r0v[r];
                    hh[r] = f2bf(m); ll[r] = f2bf(m - bf2f(hh[r]));
                }
                ushort4 hv = { hh[0], hh[1], hh[2], hh[3] };
                ushort4 lv = { ll[0], ll[1], ll[2], ll[3] };
                *(ushort4*)(Oh + ob) = hv;
                *(ushort4*)(Ol + ob) = lv;
            }
        } else {
            #pragma unroll
            for (int r = 0; r < 4; ++r) {
                int c = mt * 16 + fq * 4 + r;
                RES[((size_t)b * NT + t) * DMODEL + c * 48 + ho] = r0v[r];
            }
        }
    }
}

// ---------------- rmsnorm over D_MODEL -> bf16 hi/lo planes ----------------
__global__ __launch_bounds__(256) void k_rmsnorm(const float* __restrict__ in,
    const float* __restrict__ w, u16* __restrict__ oh, u16* __restrict__ ol)
{
    int row = blockIdx.x;
    int tid = threadIdx.x;
    const float* p = in + (size_t)row * DMODEL;
    float v[6]; float ss = 0.f;
    #pragma unroll
    for (int j = 0; j < 6; ++j) { v[j] = p[tid + j * 256]; ss = fmaf(v[j], v[j], ss); }
    #pragma unroll
    for (int off = 1; off < 64; off <<= 1) ss += __shfl_xor(ss, off);
    __shared__ float red[4];
    int lane = tid & 63, wv = tid >> 6;
    if (lane == 0) red[wv] = ss;
    __syncthreads();
    float tot = red[0] + red[1] + red[2] + red[3];
    float sc = rsqrtf(tot * (1.0f / DMODEL) + 1e-5f);
    #pragma unroll
    for (int j = 0; j < 6; ++j) {
        int col = tid + j * 256;
        float xv = v[j] * sc * w[col];
        u16 h = f2bf(xv);
        oh[(size_t)row * DMODEL + col] = h;
        ol[(size_t)row * DMODEL + col] = f2bf(xv - bf2f(h));
    }
}

// ---------------- split fp32 -> bf16 hi/lo (n divisible by 4) ----------------
__global__ __launch_bounds__(256) void k_split(const float* __restrict__ src,
    u16* __restrict__ dh, u16* __restrict__ dl, int n4)
{
    int idx = blockIdx.x * 256 + threadIdx.x;
    if (idx >= n4) return;
    float4 v = ((const float4*)src)[idx];
    u16 h0 = f2bf(v.x), h1 = f2bf(v.y), h2 = f2bf(v.z), h3 = f2bf(v.w);
    u16 l0 = f2bf(v.x - bf2f(h0)), l1 = f2bf(v.y - bf2f(h1));
    u16 l2 = f2bf(v.z - bf2f(h2)), l3 = f2bf(v.w - bf2f(h3));
    uint2 hv = { (u32)h0 | ((u32)h1 << 16), (u32)h2 | ((u32)h3 << 16) };
    uint2 lv = { (u32)l0 | ((u32)l1 << 16), (u32)l2 | ((u32)l3 << 16) };
    ((uint2*)dh)[idx] = hv;
    ((uint2*)dl)[idx] = lv;
}

// ---------------- fused per-layer weight split: xproj (vec4) + dt_w pad ----------------
__global__ __launch_bounds__(256) void k_wsplit2(
    const float* __restrict__ xpw, u16* __restrict__ xh, u16* __restrict__ xl,
    const float* __restrict__ dtw, u16* __restrict__ dh, u16* __restrict__ dl)
{
    int idx = blockIdx.x * 256 + threadIdx.x;
    if (idx < 98304) {
        float4 v = ((const float4*)xpw)[idx];
        u16 h0 = f2bf(v.x), h1 = f2bf(v.y), h2 = f2bf(v.z), h3 = f2bf(v.w);
        u16 l0 = f2bf(v.x - bf2f(h0)), l1 = f2bf(v.y - bf2f(h1));
        u16 l2 = f2bf(v.z - bf2f(h2)), l3 = f2bf(v.w - bf2f(h3));
        uint2 hv = { (u32)h0 | ((u32)h1 << 16), (u32)h2 | ((u32)h3 << 16) };
        uint2 lv = { (u32)l0 | ((u32)l1 << 16), (u32)l2 | ((u32)l3 << 16) };
        ((uint2*)xh)[idx] = hv;
        ((uint2*)xl)[idx] = lv;
        return;
    }
    int j = idx - 98304;
    if (j >= DINNER * 128) return;
    int col = j & 127, row = j >> 7;
    float v = (col < DTRANK) ? dtw[(size_t)row * DTRANK + col] : 0.f;
    u16 h = f2bf(v);
    dh[j] = h;
    dl[j] = f2bf(v - bf2f(h));
}

// ---------------- 128x128 MFMA GEMM (BK=64) for dt / x_proj ----------------
template<int EPI>
__global__ __launch_bounds__(256) void k_gemm_mfma(
    const u16* __restrict__ Ahi, const u16* __restrict__ Alo, int lda,
    const u16* __restrict__ Bhi, const u16* __restrict__ Blo, int ldb,
    float* __restrict__ C, int ldc, int Ktot,
    const float* __restrict__ bias, size_t zStride)
{
    __shared__ __align__(16) u16 lds[4][8192];
    const int tid = threadIdx.x;
    const int m0 = blockIdx.y * 128, n0 = blockIdx.x * 128;
    const int kPer = Ktot / gridDim.z;
    const int kBase = blockIdx.z * kPer;
    const int wid = tid >> 6, lane = tid & 63;
    const int wr = wid >> 1, wc = wid & 1;
    const int fr = lane & 15, fq = lane >> 4;
    const int srow  = tid >> 3;
    const int sslot = (tid & 7) ^ ((tid >> 3) & 7);

    f32x4 acc[4][4];
    #pragma unroll
    for (int mi = 0; mi < 4; ++mi)
        #pragma unroll
        for (int ni = 0; ni < 4; ++ni) acc[mi][ni] = (f32x4){0.f, 0.f, 0.f, 0.f};

    for (int k0 = kBase; k0 < kBase + kPer; k0 += 64) {
        #pragma unroll
        for (int i = 0; i < 4; ++i) {
            int row = i * 32 + srow;
            size_t offA = (size_t)(m0 + row) * lda + k0 + sslot * 8;
            size_t offB = (size_t)(n0 + row) * ldb + k0 + sslot * 8;
            u16* lb = &lds[0][0] + i * 2048 + (wid << 9);
            GLD(Ahi + offA, lb);
            GLD(Alo + offA, lb + 8192);
            GLD(Bhi + offB, lb + 16384);
            GLD(Blo + offB, lb + 24576);
        }
        __syncthreads();
        #pragma unroll
        for (int h = 0; h < 2; ++h) {
            bf16x8 ah[4], al[4], bh[4], bl[4];
            #pragma unroll
            for (int mi = 0; mi < 4; ++mi) {
                int row = wr * 64 + mi * 16 + fr;
                int sl  = (h * 4 + fq) ^ (row & 7);
                const u16* p = &lds[0][row * 64 + sl * 8];
                ah[mi] = *(const bf16x8*)p;
                al[mi] = *(const bf16x8*)(p + 8192);
            }
            #pragma unroll
            for (int ni = 0; ni < 4; ++ni) {
                int row = wc * 64 + ni * 16 + fr;
                int sl  = (h * 4 + fq) ^ (row & 7);
                const u16* p = &lds[2][row * 64 + sl * 8];
                bh[ni] = *(const bf16x8*)p;
                bl[ni] = *(const bf16x8*)(p + 8192);
            }
            #pragma unroll
            for (int mi = 0; mi < 4; ++mi)
                #pragma unroll
                for (int ni = 0; ni < 4; ++ni) {
                    acc[mi][ni] = __builtin_amdgcn_mfma_f32_16x16x32_bf16(ah[mi], bh[ni], acc[mi][ni], 0, 0, 0);
                    acc[mi][ni] = __builtin_amdgcn_mfma_f32_16x16x32_bf16(ah[mi], bl[ni], acc[mi][ni], 0, 0, 0);
                    acc[mi][ni] = __builtin_amdgcn_mfma_f32_16x16x32_bf16(al[mi], bh[ni], acc[mi][ni], 0, 0, 0);
                }
        }
        __syncthreads();
    }

    float* Cz = C + (EPI == 0 ? (size_t)blockIdx.z * zStride : (size_t)0);
    #pragma unroll
    for (int mi = 0; mi < 4; ++mi)
        #pragma unroll
        for (int ni = 0; ni < 4; ++ni) {
            int gr = m0 + wr * 64 + mi * 16 + fq * 4;
            int gc = n0 + wc * 64 + ni * 16 + fr;
            float* cp = Cz + (size_t)gr * ldc + gc;
            #pragma unroll
            for (int r = 0; r < 4; ++r) {
                float v = acc[mi][ni][r];
                if (EPI == 1) v = softplusf(v + bias[gc]);
                if (EPI == 2) v += cp[(size_t)r * ldc];
                cp[(size_t)r * ldc] = v;
            }
        }
}

// ---------------- 256xBN deep-phased MFMA GEMM (BK=32, 8 waves, free-run) ----------------
// T1 chunked-bijective XCD swizzle (nwg % 8 == 0 for all launches): XCD j's
// concurrent blocks become consecutive tiles -> A-panel reuse hits per-XCD L2.
template<int EPI, int BN>
__global__ __launch_bounds__(512, 2) void k_gemm256(
    const u16* __restrict__ Ahi, const u16* __restrict__ Alo, int lda,
    const u16* __restrict__ Bhi, const u16* __restrict__ Blo, int ldb,
    float* __restrict__ C, int ldc, int Ktot)
{
    constexpr int BM = 256;
    constexpr int TILE = (2 * BM + 2 * BN) * 64;       // bytes per K-tile
    constexpr int NUNITS = TILE / 8192;
    constexpr int NI = BN / 64;                        // ni tiles per wave
    __shared__ __align__(16) u16 lds[2 * TILE / 2];
    const int tid = threadIdx.x;
    const int nwg = gridDim.x * gridDim.y;
    const int lin = blockIdx.y * gridDim.x + blockIdx.x;
    const int swz = (lin & 7) * (nwg >> 3) + (lin >> 3);
    const int m0 = (swz / gridDim.x) * BM, n0 = (swz % gridDim.x) * BN;
    const int wid = tid >> 6, lane = tid & 63;
    const int wr = wid >> 2, wc = wid & 3;             // 2 x 4 waves
    const int fr = lane & 15, fq = lane >> 4;
    const int nK = Ktot / 32;

    auto STAGE = [&](int buf, int k0, int u) {
        int goff = u * 8192 + tid * 16;                // byte in packed tile
        int plane, rb;
        if (goff < BM * 64)                 { plane = 0; rb = goff; }
        else if (goff < 2 * BM * 64)        { plane = 1; rb = goff - BM * 64; }
        else if (goff < 2 * BM * 64 + BN * 64) { plane = 2; rb = goff - 2 * BM * 64; }
        else                                { plane = 3; rb = goff - 2 * BM * 64 - BN * 64; }
        int row  = rb >> 6;
        int slot = (rb >> 4) & 3;
        int ss   = slot ^ ((row >> 1) & 3);
        const u16* gp;
        if (plane == 0)      gp = Ahi + (size_t)(m0 + row) * lda + k0 + ss * 8;
        else if (plane == 1) gp = Alo + (size_t)(m0 + row) * lda + k0 + ss * 8;
        else if (plane == 2) gp = Bhi + (size_t)(n0 + row) * ldb + k0 + ss * 8;
        else                 gp = Blo + (size_t)(n0 + row) * ldb + k0 + ss * 8;
        u16* ldst = lds + ((size_t)buf * TILE + (size_t)u * 8192 + (size_t)wid * 1024) / 2;
        GLD(gp, ldst);
    };

    f32x4 acc[8][NI];
    #pragma unroll
    for (int mi = 0; mi < 8; ++mi)
        #pragma unroll
        for (int ni = 0; ni < NI; ++ni) acc[mi][ni] = (f32x4){0.f, 0.f, 0.f, 0.f};

    #pragma unroll
    for (int u = 0; u < NUNITS; ++u) STAGE(0, 0, u);

    for (int kt = 0; kt < nK; ++kt) {
        const int cur = kt & 1;
        __syncthreads();
        const int k1 = (kt + 1) * 32;
        const bool pf = (kt + 1 < nK);
        bf16x8 bh[NI], bl[NI];
        #pragma unroll
        for (int ni = 0; ni < NI; ++ni) {
            int row = wc * (BN / 4) + ni * 16 + fr;
            int sl  = fq ^ ((row >> 1) & 3);
            const u16* p = lds + ((size_t)cur * TILE + 2 * BM * 64 + (size_t)row * 64 + (size_t)sl * 16) / 2;
            bh[ni] = *(const bf16x8*)p;
            bl[ni] = *(const bf16x8*)(p + BN * 32);
        }
        #pragma unroll
        for (int q = 0; q < 4; ++q) {
            if (pf) {
                #pragma unroll
                for (int u = (q * NUNITS) / 4; u < ((q + 1) * NUNITS) / 4; ++u)
                    STAGE(cur ^ 1, k1, u);
            }
            bf16x8 ah[2], al[2];
            #pragma unroll
            for (int j = 0; j < 2; ++j) {
                int row = wr * 128 + (2 * q + j) * 16 + fr;
                int sl  = fq ^ ((row >> 1) & 3);
                const u16* p = lds + ((size_t)cur * TILE + (size_t)row * 64 + (size_t)sl * 16) / 2;
                ah[j] = *(const bf16x8*)p;
                al[j] = *(const bf16x8*)(p + BM * 32);
            }
            __builtin_amdgcn_s_setprio(1);
            #pragma unroll
            for (int j = 0; j < 2; ++j)
                #pragma unroll
                for (int ni = 0; ni < NI; ++ni) {
                    acc[2 * q + j][ni] = __builtin_amdgcn_mfma_f32_16x16x32_bf16(ah[j], bh[ni], acc[2 * q + j][ni], 0, 0, 0);
                    acc[2 * q + j][ni] = __builtin_amdgcn_mfma_f32_16x16x32_bf16(ah[j], bl[ni], acc[2 * q + j][ni], 0, 0, 0);
                    acc[2 * q + j][ni] = __builtin_amdgcn_mfma_f32_16x16x32_bf16(al[j], bh[ni], acc[2 * q + j][ni], 0, 0, 0);
                }
            __builtin_amdgcn_s_setprio(0);
        }
    }

    #pragma unroll
    for (int mi = 0; mi < 8; ++mi)
        #pragma unroll
        for (int ni = 0; ni < NI; ++ni) {
            int gr = m0 + wr * 128 + mi * 16 + fq * 4;
            int gc = n0 + wc * (BN / 4) + ni * 16 + fr;
            float* cp = C + (size_t)gr * ldc + gc;
            #pragma unroll
            for (int r = 0; r < 4; ++r) {
                float v = acc[mi][ni][r];
                if (EPI == 2) v += cp[(size_t)r * ldc];
                cp[(size_t)r * ldc] = v;
            }
        }
}

// ---------------- depthwise causal conv1d(k=4)+bias+silu -> u hi/lo ----------------
__global__ __launch_bounds__(256) void k_conv1d(
    const float* __restrict__ xz, const float* __restrict__ w,
    const float* __restrict__ bias, u16* __restrict__ uh, u16* __restrict__ ul)
{
    constexpr int CT = 16;
    const int d  = (blockIdx.x * 256 + threadIdx.x) * 2;
    const int t0 = blockIdx.y * CT;
    const int b  = blockIdx.z;
    float4 w0 = *(const float4*)(w + (size_t)d * 4);
    float4 w1 = *(const float4*)(w + (size_t)(d + 1) * 4);
    float2 bb = *(const float2*)(bias + d);
    const float* xp = xz + ((size_t)b * NT + t0) * (2 * DINNER) + d;
    float2 a0 = {0.f, 0.f}, a1 = {0.f, 0.f}, a2 = {0.f, 0.f};
    if (t0 > 0) {
        a0 = *(const float2*)(xp - 3 * 2 * DINNER);
        a1 = *(const float2*)(xp - 2 * 2 * DINNER);
        a2 = *(const float2*)(xp - 1 * 2 * DINNER);
    }
    u32* uhp = (u32*)(uh + ((size_t)b * NT + t0) * DINNER + d);
    u32* ulp = (u32*)(ul + ((size_t)b * NT + t0) * DINNER + d);
    #pragma unroll
    for (int t = 0; t < CT; ++t) {
        float2 a3 = *(const float2*)(xp + (size_t)t * 2 * DINNER);
        float o0 = siluf(bb.x + a0.x * w0.x + a1.x * w0.y + a2.x * w0.z + a3.x * w0.w);
        float o1 = siluf(bb.y + a0.y * w1.x + a1.y * w1.y + a2.y * w1.z + a3.y * w1.w);
        u16 h0 = f2bf(o0), h1 = f2bf(o1);
        u16 l0 = f2bf(o0 - bf2f(h0)), l1 = f2bf(o1 - bf2f(h1));
        uhp[(size_t)t * (DINNER / 2)] = (u32)h0 | ((u32)h1 << 16);
        ulp[(size_t)t * (DINNER / 2)] = (u32)l0 | ((u32)l1 << 16);
        a0 = a1; a1 = a2; a2 = a3;
    }
}

// ---------------- reduce 4 split-K slabs of x_proj + split to hi/lo ----------------
__global__ __launch_bounds__(256) void k_reduce_split(const float* __restrict__ part,
    float* __restrict__ out, u16* __restrict__ dh, u16* __restrict__ dl)
{
    int idx = blockIdx.x * 256 + threadIdx.x;
    if (idx >= MROWS * 128) return;
    float s = part[idx] + part[(size_t)1 * MROWS * 128 + idx]
            + part[(size_t)2 * MROWS * 128 + idx] + part[(size_t)3 * MROWS * 128 + idx];
    out[idx] = s;
    u16 h = f2bf(s);
    dh[idx] = h;
    dl[idx] = f2bf(s - bf2f(h));
}

// ---------------- scan pass 1: lane-per-d local chunk scan (all regs) ----------------
__global__ __launch_bounds__(256) void k_scan_p1(
    const float* __restrict__ xz, const u16* __restrict__ uh, const u16* __restrict__ ul,
    const float* __restrict__ xdbl, const float* __restrict__ A_log,
    float* __restrict__ HP, float* __restrict__ SS)
{
    const int d = blockIdx.x * 256 + threadIdx.x;
    const int c = blockIdx.y, b = blockIdx.z;
    const float L2E = 1.44269504088896340736f;
    f32x4 al0 = *(const f32x4*)(A_log + (size_t)d * DSTATE + 0);
    f32x4 al1 = *(const f32x4*)(A_log + (size_t)d * DSTATE + 4);
    f32x4 al2 = *(const f32x4*)(A_log + (size_t)d * DSTATE + 8);
    f32x4 al3 = *(const f32x4*)(A_log + (size_t)d * DSTATE + 12);
    f32x4 aa0, aa1, aa2, aa3;
    #pragma unroll
    for (int j = 0; j < 4; ++j) {
        aa0[j] = -__expf(al0[j]) * L2E;
        aa1[j] = -__expf(al1[j]) * L2E;
        aa2[j] = -__expf(al2[j]) * L2E;
        aa3[j] = -__expf(al3[j]) * L2E;
    }
    const int t0 = c * CHKT;
    const float* dP = xz + ((size_t)b * NT + t0) * (2 * DINNER) + d;
    const u16* uhP = uh + ((size_t)b * NT + t0) * DINNER + d;
    const u16* ulP = ul + ((size_t)b * NT + t0) * DINNER + d;
    const float* bP = xdbl + ((size_t)b * NT + t0) * 128 + DTRANK;
    f32x4 h0 = {0.f,0.f,0.f,0.f}, h1 = h0, h2 = h0, h3 = h0;
    float S = 0.f;
    float dlt = dP[0];
    float uu = bf2f(uhP[0]) + bf2f(ulP[0]);
    for (int t = 0; t < CHKT; ++t) {
        float dlt_n = 0.f, uu_n = 0.f;
        if (t + 1 < CHKT) {
            dlt_n = dP[2 * DINNER];
            uu_n = bf2f(uhP[DINNER]) + bf2f(ulP[DINNER]);
        }
        f32x4 B0 = *(const f32x4*)(bP + 0);
        f32x4 B1 = *(const f32x4*)(bP + 4);
        f32x4 B2 = *(const f32x4*)(bP + 8);
        f32x4 B3 = *(const f32x4*)(bP + 12);
        float du = dlt * uu;
        S += dlt;
        h0 = exp2v(dlt * aa0) * h0 + du * B0;
        h1 = exp2v(dlt * aa1) * h1 + du * B1;
        h2 = exp2v(dlt * aa2) * h2 + du * B2;
        h3 = exp2v(dlt * aa3) * h3 + du * B3;
        dP += 2 * DINNER; uhP += DINNER; ulP += DINNER; bP += 128;
        dlt = dlt_n; uu = uu_n;
    }
    size_t a = (((size_t)(b * NCHK + c) * DINNER) + d) * DSTATE;
    *(f32x4*)(HP + a + 0)  = h0;
    *(f32x4*)(HP + a + 4)  = h1;
    *(f32x4*)(HP + a + 8)  = h2;
    *(f32x4*)(HP + a + 12) = h3;
    SS[(size_t)(b * NCHK + c) * DINNER + d] = S;
}

// ---------------- scan pass 2: chunk-prefix; HP becomes h_init per chunk ----------------
__global__ __launch_bounds__(256) void k_scan_p2(float* __restrict__ HP,
    const float* __restrict__ SS, const float* __restrict__ A_log)
{
    int idx = blockIdx.x * 256 + threadIdx.x;
    if (idx >= NB * DINNER * DSTATE) return;
    int s = idx & (DSTATE - 1);
    int d = (idx >> 4) % DINNER;
    int b = idx / (DINNER * DSTATE);
    const float L2E = 1.44269504088896340736f;
    float aa = -__expf(A_log[d * DSTATE + s]) * L2E;
    float h = 0.f;
    #pragma unroll
    for (int c = 0; c < NCHK; ++c) {
        size_t a = (((size_t)(b * NCHK + c) * DINNER) + d) * DSTATE + s;
        float hc = HP[a];
        float P = exp2f(aa * SS[(size_t)(b * NCHK + c) * DINNER + d]);
        HP[a] = h;
        h = fmaf(P, h, hc);
    }
}

// ---------------- scan pass 3: lane-per-d chunk scan with h_init (all regs) ----------------
__global__ __launch_bounds__(256) void k_scan_p3(
    const float* __restrict__ xz,
    u16* uh, u16* ul,
    const float* __restrict__ xdbl,
    const float* __restrict__ A_log, const float* __restrict__ Dp,
    const float* __restrict__ HP)
{
    const int d = blockIdx.x * 256 + threadIdx.x;
    const int c = blockIdx.y, b = blockIdx.z;
    const float L2E = 1.44269504088896340736f;
    f32x4 al0 = *(const f32x4*)(A_log + (size_t)d * DSTATE + 0);
    f32x4 al1 = *(const f32x4*)(A_log + (size_t)d * DSTATE + 4);
    f32x4 al2 = *(const f32x4*)(A_log + (size_t)d * DSTATE + 8);
    f32x4 al3 = *(const f32x4*)(A_log + (size_t)d * DSTATE + 12);
    f32x4 aa0, aa1, aa2, aa3;
    #pragma unroll
    for (int j = 0; j < 4; ++j) {
        aa0[j] = -__expf(al0[j]) * L2E;
        aa1[j] = -__expf(al1[j]) * L2E;
        aa2[j] = -__expf(al2[j]) * L2E;
        aa3[j] = -__expf(al3[j]) * L2E;
    }
    const float dp = Dp[d];
    const int t0 = c * CHKT;
    const float* dP = xz + ((size_t)b * NT + t0) * (2 * DINNER) + d;
    const float* zP = dP + DINNER;
    const u16* uhP = uh + ((size_t)b * NT + t0) * DINNER + d;
    const u16* ulP = ul + ((size_t)b * NT + t0) * DINNER + d;
    u16* yhP = (u16*)uhP;
    u16* ylP = (u16*)ulP;
    const float* bP = xdbl + ((size_t)b * NT + t0) * 128 + DTRANK;
    size_t ha = (((size_t)(b * NCHK + c) * DINNER) + d) * DSTATE;
    f32x4 h0 = *(const f32x4*)(HP + ha + 0);
    f32x4 h1 = *(const f32x4*)(HP + ha + 4);
    f32x4 h2 = *(const f32x4*)(HP + ha + 8);
    f32x4 h3 = *(const f32x4*)(HP + ha + 12);
    float dlt = dP[0], zz = zP[0];
    float uu = bf2f(uhP[0]) + bf2f(ulP[0]);
    for (int t = 0; t < CHKT; ++t) {
        float dlt_n = 0.f, uu_n = 0.f, zz_n = 0.f;
        if (t + 1 < CHKT) {
            dlt_n = dP[2 * DINNER]; zz_n = zP[2 * DINNER];
            uu_n = bf2f(uhP[DINNER]) + bf2f(ulP[DINNER]);
        }
        f32x4 B0 = *(const f32x4*)(bP + 0);
        f32x4 B1 = *(const f32x4*)(bP + 4);
        f32x4 B2 = *(const f32x4*)(bP + 8);
        f32x4 B3 = *(const f32x4*)(bP + 12);
        f32x4 C0 = *(const f32x4*)(bP + DSTATE + 0);
        f32x4 C1 = *(const f32x4*)(bP + DSTATE + 4);
        f32x4 C2 = *(const f32x4*)(bP + DSTATE + 8);
        f32x4 C3 = *(const f32x4*)(bP + DSTATE + 12);
        float du = dlt * uu;
        h0 = exp2v(dlt * aa0) * h0 + du * B0;
        h1 = exp2v(dlt * aa1) * h1 + du * B1;
        h2 = exp2v(dlt * aa2) * h2 + du * B2;
        h3 = exp2v(dlt * aa3) * h3 + du * B3;
        f32x4 pv = h0 * C0 + h1 * C1 + h2 * C2 + h3 * C3;
        float p = (pv[0] + pv[1]) + (pv[2] + pv[3]);
        float yv = (p + uu * dp) * siluf(zz);
        u16 hh = f2bf(yv);
        yhP[0] = hh;
        ylP[0] = f2bf(yv - bf2f(hh));
        dP += 2 * DINNER; zP += 2 * DINNER;
        uhP += DINNER; ulP += DINNER; yhP += DINNER; ylP += DINNER;
        bP += 128;
        dlt = dlt_n; zz = zz_n; uu = uu_n;
    }
}

// ---------------- final fc + silu + transpose to (B,5,T) ----------------
__global__ __launch_bounds__(256) void k_fc(const float* __restrict__ hR,
    const float* __restrict__ w, const float* __restrict__ bias,
    float* __restrict__ out)
{
    int row = blockIdx.x;
    int tid = threadIdx.x;
    const float* p = hR + (size_t)row * DMODEL;
    float acc[NCLASS] = {0.f, 0.f, 0.f, 0.f, 0.f};
    #pragma unroll
    for (int j = 0; j < 6; ++j) {
        int col = tid + j * 256;
        float v = p[col];
        #pragma unroll
        for (int c = 0; c < NCLASS; ++c)
            acc[c] = fmaf(v, w[c * DMODEL + col], acc[c]);
    }
    #pragma unroll
    for (int c = 0; c < NCLASS; ++c)
        #pragma unroll
        for (int off = 1; off < 64; off <<= 1)
            acc[c] += __shfl_xor(acc[c], off);
    __shared__ float red[4][NCLASS];
    int lane = tid & 63, wv = tid >> 6;
    if (lane == 0)
        for (int c = 0; c < NCLASS; ++c) red[wv][c] = acc[c];
    __syncthreads();
    if (tid < NCLASS) {
        float s = red[0][tid] + red[1][tid] + red[2][tid] + red[3][tid] + bias[tid];
        int b = row >> 10, t = row & (NT - 1);
        out[((size_t)b * NCLASS + tid) * NT + t] = siluf(s);
    }
}

extern "C" void kernel_launch(void* const* d_in, const int* in_sizes, int n_in,
                              void* d_out, int out_size, void* d_ws, size_t ws_size,
                              hipStream_t stream)
{
    const float* x      = (const float*)d_in[0];
    const float* c1a_w  = (const float*)d_in[1];
    const float* c1a_b  = (const float*)d_in[2];
    const float* c1b_w  = (const float*)d_in[3];
    const float* c1b_b  = (const float*)d_in[4];
    const float* c1s_w  = (const float*)d_in[5];
    const float* c1s_b  = (const float*)d_in[6];
    const float* c2a_w  = (const float*)d_in[7];
    const float* c2a_b  = (const float*)d_in[8];
    const float* c2b_w  = (const float*)d_in[9];
    const float* c2b_b  = (const float*)d_in[10];
    const float* norm_w = (const float*)d_in[11];
    const float* in_w   = (const float*)d_in[12];
    const float* conv_w = (const float*)d_in[13];
    const float* conv_b = (const float*)d_in[14];
    const float* xproj_w= (const float*)d_in[15];
    const float* dt_w   = (const float*)d_in[16];
    const float* dt_b   = (const float*)d_in[17];
    const float* A_log  = (const float*)d_in[18];
    const float* Dp     = (const float*)d_in[19];
    const float* out_w  = (const float*)d_in[20];
    const float* fc_w   = (const float*)d_in[21];
    const float* fc_b   = (const float*)d_in[22];
    float* outp = (float*)d_out;
    (void)in_sizes; (void)n_in; (void)out_size; (void)ws_size;

    char* base = (char*)d_ws;
    size_t off = 0;
    auto takeB = [&](size_t bytes) { void* p = base + off; off = (off + bytes + 255) & ~(size_t)255; return p; };
    float* HCAT = (float*)takeB((size_t)NB * NDIM * NT * 4);
    float* XZ   = (float*)takeB((size_t)MROWS * 2 * DINNER * 4);
    float* RES  = (float*)takeB((size_t)MROWS * DMODEL * 4);
    u16*   XNh  = (u16*)takeB((size_t)MROWS * DMODEL * 2);
    u16*   XNl  = (u16*)takeB((size_t)MROWS * DMODEL * 2);
    u16*   Uh   = (u16*)takeB((size_t)MROWS * DINNER * 2);
    u16*   Ul   = (u16*)takeB((size_t)MROWS * DINNER * 2);
    float* XDBL = (float*)takeB((size_t)MROWS * 128 * 4);
    float* XPART= (float*)takeB((size_t)4 * MROWS * 128 * 4);
    u16*   XDh  = (u16*)takeB((size_t)MROWS * 128 * 2);
    u16*   XDl  = (u16*)takeB((size_t)MROWS * 128 * 2);
    u16*   Wh   = (u16*)takeB((size_t)9437184 * 2);
    u16*   Wl   = (u16*)takeB((size_t)9437184 * 2);
    u16*   DTh  = (u16*)takeB((size_t)DINNER * 128 * 2);
    u16*   DTl  = (u16*)takeB((size_t)DINNER * 128 * 2);
    float* HP   = (float*)takeB((size_t)NB * NCHK * DINNER * DSTATE * 4);
    float* SS   = (float*)takeB((size_t)NB * NCHK * DINNER * 4);
    u16*   CW1h = (u16*)takeB(18432);
    u16*   CW1l = (u16*)takeB(18432);
    u16*   CW2h = (u16*)takeB(18432);
    u16*   CW2l = (u16*)takeB(18432);
    u16*   CW3h = (u16*)takeB(18432);
    u16*   CW3l = (u16*)takeB(18432);
    u16*   ZPAD = (u16*)takeB(256);

    u16* T1h = (u16*)XZ;
    u16* T1l = T1h + (size_t)NB * NDIM * NT * 32;
    u16* T3h = (u16*)XZ;
    u16* T3l = T3h + (size_t)NB * NDIM * NT * 32;
    u16* P1h = Uh;
    u16* P1l = Ul;

    const int n1 = NB * NDIM * NT;
    k_prep  <<<(n1 + 255) / 256, 256, 0, stream>>>(x, HCAT, ZPAD);
    k_wconv3<<<dim3(36, 3), 256, 0, stream>>>(c1b_w, CW1h, CW1l,
                                              c2a_w, CW2h, CW2l,
                                              c2b_w, CW3h, CW3l);
    k_conv1a<<<(n1 + 255) / 256, 256, 0, stream>>>(HCAT, c1a_w, c1a_b, T1h, T1l);
    k_convmfma<0><<<dim3(16, 96, NB), 256, 0, stream>>>(
        T1h, T1l, CW1h, CW1l, HCAT, c1s_w, c1s_b, nullptr, nullptr,
        c1b_b, P1h, P1l, nullptr, ZPAD);
    k_convmfma<1><<<dim3(16, 48, NB), 256, 0, stream>>>(
        P1h, P1l, CW2h, CW2l, nullptr, nullptr, nullptr, nullptr, nullptr,
        c2a_b, T3h, T3l, nullptr, ZPAD);
    k_convmfma<2><<<dim3(16, 48, NB), 256, 0, stream>>>(
        T3h, T3l, CW3h, CW3l, nullptr, nullptr, nullptr, P1h, P1l,
        c2b_b, nullptr, nullptr, RES, ZPAD);

    for (int l = 0; l < NLAYER; ++l) {
        k_rmsnorm<<<MROWS, 256, 0, stream>>>(RES, norm_w + (size_t)l * DMODEL, XNh, XNl);
        k_split<<<(9437184 / 4 + 255) / 256, 256, 0, stream>>>(
            in_w + (size_t)l * 2 * DINNER * DMODEL, Wh, Wl, 9437184 / 4);
        k_gemm256<0, 256><<<dim3(2 * DINNER / 256, MROWS / 256), 512, 0, stream>>>(
            XNh, XNl, DMODEL, Wh, Wl, DMODEL, XZ, 2 * DINNER, DMODEL);
        k_conv1d<<<dim3(DINNER / 512, NT / 16, NB), 256, 0, stream>>>(
            XZ, conv_w + (size_t)l * DINNER * 4, conv_b + (size_t)l * DINNER, Uh, Ul);
        k_wsplit2<<<(98304 + DINNER * 128 + 255) / 256, 256, 0, stream>>>(
            xproj_w + (size_t)l * 128 * DINNER, Wh, Wl,
            dt_w + (size_t)l * DINNER * DTRANK, DTh, DTl);
        k_gemm_mfma<0><<<dim3(1, MROWS / 128, 4), 256, 0, stream>>>(
            Uh, Ul, DINNER, Wh, Wl, DINNER, XPART, 128, DINNER, nullptr, (size_t)MROWS * 128);
        k_reduce_split<<<(MROWS * 128 + 255) / 256, 256, 0, stream>>>(XPART, XDBL, XDh, XDl);
        k_gemm_mfma<1><<<dim3(DINNER / 128, MROWS / 128, 1), 256, 0, stream>>>(
            XDh, XDl, 128, DTh, DTl, 128, XZ, 2 * DINNER, 128,
            dt_b + (size_t)l * DINNER, 0);
        k_scan_p1<<<dim3(DINNER / 256, NCHK, NB), 256, 0, stream>>>(
            XZ, Uh, Ul, XDBL, A_log + (size_t)l * DINNER * DSTATE, HP, SS);
        k_scan_p2<<<(NB * DINNER * DSTATE + 255) / 256, 256, 0, stream>>>(
            HP, SS, A_log + (size_t)l * DINNER * DSTATE);
        k_scan_p3<<<dim3(DINNER / 256, NCHK, NB), 256, 0, stream>>>(
            XZ, Uh, Ul, XDBL, A_log + (size_t)l * DINNER * DSTATE,
            Dp + (size_t)l * DINNER, HP);
        k_split<<<(4718592 / 4 + 255) / 256, 256, 0, stream>>>(
            out_w + (size_t)l * DMODEL * DINNER, Wh, Wl, 4718592 / 4);
        k_gemm256<2, 192><<<dim3(DMODEL / 192, MROWS / 256), 512, 0, stream>>>(
            Uh, Ul, DINNER, Wh, Wl, DINNER, RES, DMODEL, DINNER);
    }
    k_fc<<<MROWS, 256, 0, stream>>>(RES, fc_w, fc_b, outp);
}

// Round 16
// 4568.493 us; speedup vs baseline: 1.0199x; 1.0028x over previous
//
#include <hip/hip_runtime.h>
#include <cstdint>
#include <cstddef>

#define DEV static __device__ __forceinline__

typedef unsigned short u16;
typedef unsigned int   u32;
typedef __bf16 bf16x8 __attribute__((ext_vector_type(8)));
typedef float  f32x4  __attribute__((ext_vector_type(4)));

namespace {
constexpr int NB     = 8;
constexpr int NT     = 1024;
constexpr int NMEL   = 96;
constexpr int NDIM   = 192;
constexpr int NCH    = 32;
constexpr int DMODEL = 1536;
constexpr int DINNER = 3072;
constexpr int DSTATE = 16;
constexpr int DTRANK = 96;
constexpr int NLAYER = 4;
constexpr int NCLASS = 5;
constexpr int MROWS  = NB * NT;   // 8192
constexpr int NCHK   = 16;
constexpr int CHKT   = NT / NCHK; // 64
}

DEV float siluf(float x)    { return x / (1.0f + __expf(-x)); }
DEV float softplusf(float x){ return fmaxf(x, 0.0f) + log1pf(__expf(-fabsf(x))); }

DEV u16 f2bf(float f) {
    u32 u = __float_as_uint(f);
    u32 r = u + 0x7FFFu + ((u >> 16) & 1u);
    return (u16)(r >> 16);
}
DEV float bf2f(u16 h) { return __uint_as_float(((u32)h) << 16); }

DEV f32x4 exp2v(f32x4 x) {
    f32x4 r;
    r[0] = exp2f(x[0]); r[1] = exp2f(x[1]);
    r[2] = exp2f(x[2]); r[3] = exp2f(x[3]);
    return r;
}

#define GLD(gp, lp) __builtin_amdgcn_global_load_lds( \
    (const __attribute__((address_space(1))) u32*)(const void*)(gp), \
    (__attribute__((address_space(3))) u32*)(void*)(lp), 16, 0, 0)

// ---------------- prep: x -> hcat (B,192,T): [x ; relu(diff)]; also zero ZPAD ----------------
__global__ __launch_bounds__(256) void k_prep(const float* __restrict__ x,
                                              float* __restrict__ hcat,
                                              u16* __restrict__ zpad)
{
    if (blockIdx.x == 0 && threadIdx.x < 128) zpad[threadIdx.x] = 0;
    int idx = blockIdx.x * 256 + threadIdx.x;
    if (idx >= NB * NDIM * NT) return;
    int t = idx & (NT - 1);
    int m = (idx >> 10) % NDIM;
    int b = idx / (NDIM * NT);
    float v;
    if (m < NMEL) {
        v = x[((size_t)b * NMEL + m) * NT + t];
    } else {
        int mm = m - NMEL;
        v = 0.f;
        if (t > 0) {
            const float* p = x + ((size_t)b * NMEL + mm) * NT + t;
            v = fmaxf(p[0] - p[-1], 0.f);
        }
    }
    hcat[idx] = v;
}

// ---------------- conv weight prep x3: (32,32,3,3) -> [tap][cout][ci] hi/lo ----------------
__global__ __launch_bounds__(256) void k_wconv3(
    const float* __restrict__ w0, u16* __restrict__ dh0, u16* __restrict__ dl0,
    const float* __restrict__ w1, u16* __restrict__ dh1, u16* __restrict__ dl1,
    const float* __restrict__ w2, u16* __restrict__ dh2, u16* __restrict__ dl2)
{
    int idx = blockIdx.x * 256 + threadIdx.x;
    if (idx >= 9216) return;
    const float* w = (blockIdx.y == 0) ? w0 : (blockIdx.y == 1) ? w1 : w2;
    u16* dh = (blockIdx.y == 0) ? dh0 : (blockIdx.y == 1) ? dh1 : dh2;
    u16* dl = (blockIdx.y == 0) ? dl0 : (blockIdx.y == 1) ? dl1 : dl2;
    int ci = idx & 31, cout = (idx >> 5) & 31, tap = idx >> 10;
    float v = w[((size_t)cout * 32 + ci) * 9 + tap];
    u16 h = f2bf(v);
    dh[idx] = h;
    dl[idx] = f2bf(v - bf2f(h));
}

// ---------------- conv1a (1->32, 3x3) + silu -> NHWC bf16 hi/lo ----------------
__global__ __launch_bounds__(256) void k_conv1a(const float* __restrict__ hcat,
    const float* __restrict__ w, const float* __restrict__ bias,
    u16* __restrict__ oh, u16* __restrict__ ol)   // (B,192,T,32)
{
    int idx = blockIdx.x * 256 + threadIdx.x;
    if (idx >= NB * NDIM * NT) return;
    int t = idx & (NT - 1);
    int h = (idx >> 10) % NDIM;
    int b = idx / (NDIM * NT);
    float in[3][3];
    #pragma unroll
    for (int dh = 0; dh < 3; ++dh)
        #pragma unroll
        for (int dw = 0; dw < 3; ++dw) {
            int hh = h + dh - 1, tt = t + dw - 1;
            in[dh][dw] = (hh >= 0 && hh < NDIM && tt >= 0 && tt < NT)
                       ? hcat[((size_t)b * NDIM + hh) * NT + tt] : 0.f;
        }
    u16 hb[32], lb[32];
    #pragma unroll
    for (int c = 0; c < NCH; ++c) {
        float acc = bias[c];
        #pragma unroll
        for (int dh = 0; dh < 3; ++dh)
            #pragma unroll
            for (int dw = 0; dw < 3; ++dw)
                acc = fmaf(in[dh][dw], w[c * 9 + dh * 3 + dw], acc);
        float o = siluf(acc);
        u16 hh2 = f2bf(o);
        hb[c] = hh2;
        lb[c] = f2bf(o - bf2f(hh2));
    }
    size_t ob = (((size_t)b * NDIM + h) * NT + t) * 32;
    #pragma unroll
    for (int j = 0; j < 8; ++j) {
        ushort4 hv = { hb[j*4], hb[j*4+1], hb[j*4+2], hb[j*4+3] };
        ushort4 lv = { lb[j*4], lb[j*4+1], lb[j*4+2], lb[j*4+3] };
        *(ushort4*)(oh + ob + j * 4) = hv;
        *(ushort4*)(ol + ob + j * 4) = lv;
    }
}

// ---------------- MFMA implicit-GEMM conv 32->32 3x3 (NHWC bf16 hi/lo) ----------------
template<int VAR>
__global__ __launch_bounds__(256) void k_convmfma(
    const u16* __restrict__ Xh, const u16* __restrict__ Xl,
    const u16* __restrict__ CWh, const u16* __restrict__ CWl,
    const float* __restrict__ hcat, const float* __restrict__ sw, const float* __restrict__ sb,
    const u16* __restrict__ Sh, const u16* __restrict__ Sl,
    const float* __restrict__ bias,
    u16* __restrict__ Oh, u16* __restrict__ Ol,
    float* __restrict__ RES,
    const u16* __restrict__ zeropad)
{
    constexpr int HIN = (VAR == 0) ? 192 : 96;
    __shared__ __align__(16) u16 lds[2][8448];
    const int t0 = blockIdx.x * 64;
    const int ho = blockIdx.y;
    const int b  = blockIdx.z;
    const int tid = threadIdx.x;
    const int wid = tid >> 6, lane = tid & 63;
    const int r0 = 2 * ho - 1;

    for (int cb = wid * 64; cb < 2112; cb += 256) {
        int c = cb + lane;
        int plane = (c >= 1056) ? 1 : 0;
        int cc = c - plane * 1056;
        int row = cc / 264;
        int rc  = cc - row * 264;
        int pos = rc >> 2;
        int slot = rc & 3;
        int cib = slot ^ ((pos >> 1) & 3);
        int h = r0 + row;
        int t = t0 - 1 + pos;
        const u16* bp = plane ? Xl : Xh;
        const u16* src = (h >= 0 && h < HIN && t >= 0 && t < NT)
            ? bp + (((size_t)(b * HIN + h)) * NT + t) * 32 + cib * 8
            : zeropad;
        u16* ldst = &lds[0][0] + (size_t)cb * 8;
        GLD(src, ldst);
    }
    __syncthreads();

    const int fr = lane & 15, fq = lane >> 4;
    f32x4 acc[2][2];
    #pragma unroll
    for (int pr = 0; pr < 2; ++pr)
        #pragma unroll
        for (int mt = 0; mt < 2; ++mt) acc[pr][mt] = (f32x4){0.f, 0.f, 0.f, 0.f};

    #pragma unroll
    for (int dh = 0; dh < 3; ++dh) {
        #pragma unroll
        for (int dt = 0; dt < 3; ++dt) {
            int tap = dh * 3 + dt;
            bf16x8 wh[2], wl[2];
            #pragma unroll
            for (int mt = 0; mt < 2; ++mt) {
                size_t wo = ((size_t)tap * 32 + mt * 16 + fr) * 32 + fq * 8;
                wh[mt] = *(const bf16x8*)(CWh + wo);
                wl[mt] = *(const bf16x8*)(CWl + wo);
            }
            int p = (wid << 4) + fr + dt;
            int sl = fq ^ ((p >> 1) & 3);
            #pragma unroll
            for (int pr = 0; pr < 2; ++pr) {
                int rr = pr + dh;
                const u16* lp = &lds[0][0] + ((rr * 66 + p) * 4 + sl) * 8;
                bf16x8 xh = *(const bf16x8*)lp;
                bf16x8 xl = *(const bf16x8*)(lp + 8448);
                #pragma unroll
                for (int mt = 0; mt < 2; ++mt) {
                    acc[pr][mt] = __builtin_amdgcn_mfma_f32_16x16x32_bf16(wh[mt], xh, acc[pr][mt], 0, 0, 0);
                    acc[pr][mt] = __builtin_amdgcn_mfma_f32_16x16x32_bf16(wh[mt], xl, acc[pr][mt], 0, 0, 0);
                    acc[pr][mt] = __builtin_amdgcn_mfma_f32_16x16x32_bf16(wl[mt], xh, acc[pr][mt], 0, 0, 0);
                }
            }
        }
    }

    const int t = t0 + (wid << 4) + fr;
    float hc0 = 0.f, hc1 = 0.f;
    if (VAR == 0) {
        hc0 = hcat[((size_t)(b * NDIM + 2 * ho    )) * NT + t];
        hc1 = hcat[((size_t)(b * NDIM + 2 * ho + 1)) * NT + t];
    }
    #pragma unroll
    for (int mt = 0; mt < 2; ++mt) {
        float v0[4], v1[4];
        if (VAR == 2) {
            ushort4 s0h = *(const ushort4*)(Sh + (((size_t)(b * 96 + 2 * ho    )) * NT + t) * 32 + mt * 16 + fq * 4);
            ushort4 s0l = *(const ushort4*)(Sl + (((size_t)(b * 96 + 2 * ho    )) * NT + t) * 32 + mt * 16 + fq * 4);
            ushort4 s1h = *(const ushort4*)(Sh + (((size_t)(b * 96 + 2 * ho + 1)) * NT + t) * 32 + mt * 16 + fq * 4);
            ushort4 s1l = *(const ushort4*)(Sl + (((size_t)(b * 96 + 2 * ho + 1)) * NT + t) * 32 + mt * 16 + fq * 4);
            v0[0] = bf2f(s0h.x) + bf2f(s0l.x); v0[1] = bf2f(s0h.y) + bf2f(s0l.y);
            v0[2] = bf2f(s0h.z) + bf2f(s0l.z); v0[3] = bf2f(s0h.w) + bf2f(s0l.w);
            v1[0] = bf2f(s1h.x) + bf2f(s1l.x); v1[1] = bf2f(s1h.y) + bf2f(s1l.y);
            v1[2] = bf2f(s1h.z) + bf2f(s1l.z); v1[3] = bf2f(s1h.w) + bf2f(s1l.w);
        }
        u16 hs[4], ls[4];
        float r0v[4], r1v[4];
        #pragma unroll
        for (int r = 0; r < 4; ++r) {
            int c = mt * 16 + fq * 4 + r;
            float a0 = acc[0][mt][r] + bias[c];
            float a1 = acc[1][mt][r] + bias[c];
            if (VAR == 0) {
                a0 += fmaf(hc0, sw[c], sb[c]);
                a1 += fmaf(hc1, sw[c], sb[c]);
            }
            if (VAR == 2) { a0 += v0[r]; a1 += v1[r]; }
            a0 = siluf(a0); a1 = siluf(a1);
            if (VAR == 1) { r0v[r] = a0; r1v[r] = a1; }
            else {
                float m = fmaxf(a0, a1);
                if (VAR == 2) r0v[r] = m;
                else { u16 hh = f2bf(m); hs[r] = hh; ls[r] = f2bf(m - bf2f(hh)); }
            }
        }
        if (VAR == 0) {
            size_t ob = (((size_t)(b * 96 + ho)) * NT + t) * 32 + mt * 16 + fq * 4;
            ushort4 hv = { hs[0], hs[1], hs[2], hs[3] };
            ushort4 lv = { ls[0], ls[1], ls[2], ls[3] };
            *(ushort4*)(Oh + ob) = hv;
            *(ushort4*)(Ol + ob) = lv;
        } else if (VAR == 1) {
            #pragma unroll
            for (int pr = 0; pr < 2; ++pr) {
                size_t ob = (((size_t)(b * 96 + 2 * ho + pr)) * NT + t) * 32 + mt * 16 + fq * 4;
                u16 hh[4], ll[4];
                #pragma unroll
                for (int r = 0; r < 4; ++r) {
                    float m = pr ? r1v[r] : r0v[r];
                    hh[r] = f2bf(m); ll[r] = f2bf(m - bf2f(hh[r]));
                }
                ushort4 hv = { hh[0], hh[1], hh[2], hh[3] };
                ushort4 lv = { ll[0], ll[1], ll[2], ll[3] };
                *(ushort4*)(Oh + ob) = hv;
                *(ushort4*)(Ol + ob) = lv;
            }
        } else {
            #pragma unroll
            for (int r = 0; r < 4; ++r) {
                int c = mt * 16 + fq * 4 + r;
                RES[((size_t)b * NT + t) * DMODEL + c * 48 + ho] = r0v[r];
            }
        }
    }
}

// ---------------- rmsnorm over D_MODEL -> bf16 hi/lo planes ----------------
__global__ __launch_bounds__(256) void k_rmsnorm(const float* __restrict__ in,
    const float* __restrict__ w, u16* __restrict__ oh, u16* __restrict__ ol)
{
    int row = blockIdx.x;
    int tid = threadIdx.x;
    const float* p = in + (size_t)row * DMODEL;
    float v[6]; float ss = 0.f;
    #pragma unroll
    for (int j = 0; j < 6; ++j) { v[j] = p[tid + j * 256]; ss = fmaf(v[j], v[j], ss); }
    #pragma unroll
    for (int off = 1; off < 64; off <<= 1) ss += __shfl_xor(ss, off);
    __shared__ float red[4];
    int lane = tid & 63, wv = tid >> 6;
    if (lane == 0) red[wv] = ss;
    __syncthreads();
    float tot = red[0] + red[1] + red[2] + red[3];
    float sc = rsqrtf(tot * (1.0f / DMODEL) + 1e-5f);
    #pragma unroll
    for (int j = 0; j < 6; ++j) {
        int col = tid + j * 256;
        float xv = v[j] * sc * w[col];
        u16 h = f2bf(xv);
        oh[(size_t)row * DMODEL + col] = h;
        ol[(size_t)row * DMODEL + col] = f2bf(xv - bf2f(h));
    }
}

// ---------------- split fp32 -> bf16 hi/lo (n divisible by 4) ----------------
__global__ __launch_bounds__(256) void k_split(const float* __restrict__ src,
    u16* __restrict__ dh, u16* __restrict__ dl, int n4)
{
    int idx = blockIdx.x * 256 + threadIdx.x;
    if (idx >= n4) return;
    float4 v = ((const float4*)src)[idx];
    u16 h0 = f2bf(v.x), h1 = f2bf(v.y), h2 = f2bf(v.z), h3 = f2bf(v.w);
    u16 l0 = f2bf(v.x - bf2f(h0)), l1 = f2bf(v.y - bf2f(h1));
    u16 l2 = f2bf(v.z - bf2f(h2)), l3 = f2bf(v.w - bf2f(h3));
    uint2 hv = { (u32)h0 | ((u32)h1 << 16), (u32)h2 | ((u32)h3 << 16) };
    uint2 lv = { (u32)l0 | ((u32)l1 << 16), (u32)l2 | ((u32)l3 << 16) };
    ((uint2*)dh)[idx] = hv;
    ((uint2*)dl)[idx] = lv;
}

// ---------------- fused per-layer weight split: xproj (vec4) + dt_w pad ----------------
__global__ __launch_bounds__(256) void k_wsplit2(
    const float* __restrict__ xpw, u16* __restrict__ xh, u16* __restrict__ xl,
    const float* __restrict__ dtw, u16* __restrict__ dh, u16* __restrict__ dl)
{
    int idx = blockIdx.x * 256 + threadIdx.x;
    if (idx < 98304) {
        float4 v = ((const float4*)xpw)[idx];
        u16 h0 = f2bf(v.x), h1 = f2bf(v.y), h2 = f2bf(v.z), h3 = f2bf(v.w);
        u16 l0 = f2bf(v.x - bf2f(h0)), l1 = f2bf(v.y - bf2f(h1));
        u16 l2 = f2bf(v.z - bf2f(h2)), l3 = f2bf(v.w - bf2f(h3));
        uint2 hv = { (u32)h0 | ((u32)h1 << 16), (u32)h2 | ((u32)h3 << 16) };
        uint2 lv = { (u32)l0 | ((u32)l1 << 16), (u32)l2 | ((u32)l3 << 16) };
        ((uint2*)xh)[idx] = hv;
        ((uint2*)xl)[idx] = lv;
        return;
    }
    int j = idx - 98304;
    if (j >= DINNER * 128) return;
    int col = j & 127, row = j >> 7;
    float v = (col < DTRANK) ? dtw[(size_t)row * DTRANK + col] : 0.f;
    u16 h = f2bf(v);
    dh[j] = h;
    dl[j] = f2bf(v - bf2f(h));
}

// ---------------- 128x128 MFMA GEMM (BK=64) for dt / x_proj ----------------
template<int EPI>
__global__ __launch_bounds__(256) void k_gemm_mfma(
    const u16* __restrict__ Ahi, const u16* __restrict__ Alo, int lda,
    const u16* __restrict__ Bhi, const u16* __restrict__ Blo, int ldb,
    float* __restrict__ C, int ldc, int Ktot,
    const float* __restrict__ bias, size_t zStride)
{
    __shared__ __align__(16) u16 lds[4][8192];
    const int tid = threadIdx.x;
    const int m0 = blockIdx.y * 128, n0 = blockIdx.x * 128;
    const int kPer = Ktot / gridDim.z;
    const int kBase = blockIdx.z * kPer;
    const int wid = tid >> 6, lane = tid & 63;
    const int wr = wid >> 1, wc = wid & 1;
    const int fr = lane & 15, fq = lane >> 4;
    const int srow  = tid >> 3;
    const int sslot = (tid & 7) ^ ((tid >> 3) & 7);

    f32x4 acc[4][4];
    #pragma unroll
    for (int mi = 0; mi < 4; ++mi)
        #pragma unroll
        for (int ni = 0; ni < 4; ++ni) acc[mi][ni] = (f32x4){0.f, 0.f, 0.f, 0.f};

    for (int k0 = kBase; k0 < kBase + kPer; k0 += 64) {
        #pragma unroll
        for (int i = 0; i < 4; ++i) {
            int row = i * 32 + srow;
            size_t offA = (size_t)(m0 + row) * lda + k0 + sslot * 8;
            size_t offB = (size_t)(n0 + row) * ldb + k0 + sslot * 8;
            u16* lb = &lds[0][0] + i * 2048 + (wid << 9);
            GLD(Ahi + offA, lb);
            GLD(Alo + offA, lb + 8192);
            GLD(Bhi + offB, lb + 16384);
            GLD(Blo + offB, lb + 24576);
        }
        __syncthreads();
        #pragma unroll
        for (int h = 0; h < 2; ++h) {
            bf16x8 ah[4], al[4], bh[4], bl[4];
            #pragma unroll
            for (int mi = 0; mi < 4; ++mi) {
                int row = wr * 64 + mi * 16 + fr;
                int sl  = (h * 4 + fq) ^ (row & 7);
                const u16* p = &lds[0][row * 64 + sl * 8];
                ah[mi] = *(const bf16x8*)p;
                al[mi] = *(const bf16x8*)(p + 8192);
            }
            #pragma unroll
            for (int ni = 0; ni < 4; ++ni) {
                int row = wc * 64 + ni * 16 + fr;
                int sl  = (h * 4 + fq) ^ (row & 7);
                const u16* p = &lds[2][row * 64 + sl * 8];
                bh[ni] = *(const bf16x8*)p;
                bl[ni] = *(const bf16x8*)(p + 8192);
            }
            #pragma unroll
            for (int mi = 0; mi < 4; ++mi)
                #pragma unroll
                for (int ni = 0; ni < 4; ++ni) {
                    acc[mi][ni] = __builtin_amdgcn_mfma_f32_16x16x32_bf16(ah[mi], bh[ni], acc[mi][ni], 0, 0, 0);
                    acc[mi][ni] = __builtin_amdgcn_mfma_f32_16x16x32_bf16(ah[mi], bl[ni], acc[mi][ni], 0, 0, 0);
                    acc[mi][ni] = __builtin_amdgcn_mfma_f32_16x16x32_bf16(al[mi], bh[ni], acc[mi][ni], 0, 0, 0);
                }
        }
        __syncthreads();
    }

    float* Cz = C + (EPI == 0 ? (size_t)blockIdx.z * zStride : (size_t)0);
    #pragma unroll
    for (int mi = 0; mi < 4; ++mi)
        #pragma unroll
        for (int ni = 0; ni < 4; ++ni) {
            int gr = m0 + wr * 64 + mi * 16 + fq * 4;
            int gc = n0 + wc * 64 + ni * 16 + fr;
            float* cp = Cz + (size_t)gr * ldc + gc;
            #pragma unroll
            for (int r = 0; r < 4; ++r) {
                float v = acc[mi][ni][r];
                if (EPI == 1) v = softplusf(v + bias[gc]);
                if (EPI == 2) v += cp[(size_t)r * ldc];
                cp[(size_t)r * ldc] = v;
            }
        }
}

// ---------------- 256xBN deep-phased MFMA GEMM (BK=32, 8 waves, free-run) ----------------
// SWZ=1: chunked-bijective XCD swizzle (helped out_proj gridX=8);
// SWZ=0: natural dispatch order (best for in_proj gridX=24, A-panel sharing).
template<int EPI, int BN, int SWZ>
__global__ __launch_bounds__(512, 2) void k_gemm256(
    const u16* __restrict__ Ahi, const u16* __restrict__ Alo, int lda,
    const u16* __restrict__ Bhi, const u16* __restrict__ Blo, int ldb,
    float* __restrict__ C, int ldc, int Ktot)
{
    constexpr int BM = 256;
    constexpr int TILE = (2 * BM + 2 * BN) * 64;       // bytes per K-tile
    constexpr int NUNITS = TILE / 8192;
    constexpr int NI = BN / 64;                        // ni tiles per wave
    __shared__ __align__(16) u16 lds[2 * TILE / 2];
    const int tid = threadIdx.x;
    int m0, n0;
    if (SWZ) {
        const int nwg = gridDim.x * gridDim.y;
        const int lin = blockIdx.y * gridDim.x + blockIdx.x;
        const int swz = (lin & 7) * (nwg >> 3) + (lin >> 3);
        m0 = (swz / gridDim.x) * BM;
        n0 = (swz % gridDim.x) * BN;
    } else {
        m0 = blockIdx.y * BM;
        n0 = blockIdx.x * BN;
    }
    const int wid = tid >> 6, lane = tid & 63;
    const int wr = wid >> 2, wc = wid & 3;             // 2 x 4 waves
    const int fr = lane & 15, fq = lane >> 4;
    const int nK = Ktot / 32;

    auto STAGE = [&](int buf, int k0, int u) {
        int goff = u * 8192 + tid * 16;                // byte in packed tile
        int plane, rb;
        if (goff < BM * 64)                 { plane = 0; rb = goff; }
        else if (goff < 2 * BM * 64)        { plane = 1; rb = goff - BM * 64; }
        else if (goff < 2 * BM * 64 + BN * 64) { plane = 2; rb = goff - 2 * BM * 64; }
        else                                { plane = 3; rb = goff - 2 * BM * 64 - BN * 64; }
        int row  = rb >> 6;
        int slot = (rb >> 4) & 3;
        int ss   = slot ^ ((row >> 1) & 3);
        const u16* gp;
        if (plane == 0)      gp = Ahi + (size_t)(m0 + row) * lda + k0 + ss * 8;
        else if (plane == 1) gp = Alo + (size_t)(m0 + row) * lda + k0 + ss * 8;
        else if (plane == 2) gp = Bhi + (size_t)(n0 + row) * ldb + k0 + ss * 8;
        else                 gp = Blo + (size_t)(n0 + row) * ldb + k0 + ss * 8;
        u16* ldst = lds + ((size_t)buf * TILE + (size_t)u * 8192 + (size_t)wid * 1024) / 2;
        GLD(gp, ldst);
    };

    f32x4 acc[8][NI];
    #pragma unroll
    for (int mi = 0; mi < 8; ++mi)
        #pragma unroll
        for (int ni = 0; ni < NI; ++ni) acc[mi][ni] = (f32x4){0.f, 0.f, 0.f, 0.f};

    #pragma unroll
    for (int u = 0; u < NUNITS; ++u) STAGE(0, 0, u);

    for (int kt = 0; kt < nK; ++kt) {
        const int cur = kt & 1;
        __syncthreads();
        const int k1 = (kt + 1) * 32;
        const bool pf = (kt + 1 < nK);
        bf16x8 bh[NI], bl[NI];
        #pragma unroll
        for (int ni = 0; ni < NI; ++ni) {
            int row = wc * (BN / 4) + ni * 16 + fr;
            int sl  = fq ^ ((row >> 1) & 3);
            const u16* p = lds + ((size_t)cur * TILE + 2 * BM * 64 + (size_t)row * 64 + (size_t)sl * 16) / 2;
            bh[ni] = *(const bf16x8*)p;
            bl[ni] = *(const bf16x8*)(p + BN * 32);
        }
        #pragma unroll
        for (int q = 0; q < 4; ++q) {
            if (pf) {
                #pragma unroll
                for (int u = (q * NUNITS) / 4; u < ((q + 1) * NUNITS) / 4; ++u)
                    STAGE(cur ^ 1, k1, u);
            }
            bf16x8 ah[2], al[2];
            #pragma unroll
            for (int j = 0; j < 2; ++j) {
                int row = wr * 128 + (2 * q + j) * 16 + fr;
                int sl  = fq ^ ((row >> 1) & 3);
                const u16* p = lds + ((size_t)cur * TILE + (size_t)row * 64 + (size_t)sl * 16) / 2;
                ah[j] = *(const bf16x8*)p;
                al[j] = *(const bf16x8*)(p + BM * 32);
            }
            __builtin_amdgcn_s_setprio(1);
            #pragma unroll
            for (int j = 0; j < 2; ++j)
                #pragma unroll
                for (int ni = 0; ni < NI; ++ni) {
                    acc[2 * q + j][ni] = __builtin_amdgcn_mfma_f32_16x16x32_bf16(ah[j], bh[ni], acc[2 * q + j][ni], 0, 0, 0);
                    acc[2 * q + j][ni] = __builtin_amdgcn_mfma_f32_16x16x32_bf16(ah[j], bl[ni], acc[2 * q + j][ni], 0, 0, 0);
                    acc[2 * q + j][ni] = __builtin_amdgcn_mfma_f32_16x16x32_bf16(al[j], bh[ni], acc[2 * q + j][ni], 0, 0, 0);
                }
            __builtin_amdgcn_s_setprio(0);
        }
    }

    #pragma unroll
    for (int mi = 0; mi < 8; ++mi)
        #pragma unroll
        for (int ni = 0; ni < NI; ++ni) {
            int gr = m0 + wr * 128 + mi * 16 + fq * 4;
            int gc = n0 + wc * (BN / 4) + ni * 16 + fr;
            float* cp = C + (size_t)gr * ldc + gc;
            #pragma unroll
            for (int r = 0; r < 4; ++r) {
                float v = acc[mi][ni][r];
                if (EPI == 2) v += cp[(size_t)r * ldc];
                cp[(size_t)r * ldc] = v;
            }
        }
}

// ---------------- depthwise causal conv1d(k=4)+bias+silu -> u hi/lo ----------------
__global__ __launch_bounds__(256) void k_conv1d(
    const float* __restrict__ xz, const float* __restrict__ w,
    const float* __restrict__ bias, u16* __restrict__ uh, u16* __restrict__ ul)
{
    constexpr int CT = 16;
    const int d  = (blockIdx.x * 256 + threadIdx.x) * 2;
    const int t0 = blockIdx.y * CT;
    const int b  = blockIdx.z;
    float4 w0 = *(const float4*)(w + (size_t)d * 4);
    float4 w1 = *(const float4*)(w + (size_t)(d + 1) * 4);
    float2 bb = *(const float2*)(bias + d);
    const float* xp = xz + ((size_t)b * NT + t0) * (2 * DINNER) + d;
    float2 a0 = {0.f, 0.f}, a1 = {0.f, 0.f}, a2 = {0.f, 0.f};
    if (t0 > 0) {
        a0 = *(const float2*)(xp - 3 * 2 * DINNER);
        a1 = *(const float2*)(xp - 2 * 2 * DINNER);
        a2 = *(const float2*)(xp - 1 * 2 * DINNER);
    }
    u32* uhp = (u32*)(uh + ((size_t)b * NT + t0) * DINNER + d);
    u32* ulp = (u32*)(ul + ((size_t)b * NT + t0) * DINNER + d);
    #pragma unroll
    for (int t = 0; t < CT; ++t) {
        float2 a3 = *(const float2*)(xp + (size_t)t * 2 * DINNER);
        float o0 = siluf(bb.x + a0.x * w0.x + a1.x * w0.y + a2.x * w0.z + a3.x * w0.w);
        float o1 = siluf(bb.y + a0.y * w1.x + a1.y * w1.y + a2.y * w1.z + a3.y * w1.w);
        u16 h0 = f2bf(o0), h1 = f2bf(o1);
        u16 l0 = f2bf(o0 - bf2f(h0)), l1 = f2bf(o1 - bf2f(h1));
        uhp[(size_t)t * (DINNER / 2)] = (u32)h0 | ((u32)h1 << 16);
        ulp[(size_t)t * (DINNER / 2)] = (u32)l0 | ((u32)l1 << 16);
        a0 = a1; a1 = a2; a2 = a3;
    }
}

// ---------------- reduce 4 split-K slabs of x_proj + split to hi/lo ----------------
__global__ __launch_bounds__(256) void k_reduce_split(const float* __restrict__ part,
    float* __restrict__ out, u16* __restrict__ dh, u16* __restrict__ dl)
{
    int idx = blockIdx.x * 256 + threadIdx.x;
    if (idx >= MROWS * 128) return;
    float s = part[idx] + part[(size_t)1 * MROWS * 128 + idx]
            + part[(size_t)2 * MROWS * 128 + idx] + part[(size_t)3 * MROWS * 128 + idx];
    out[idx] = s;
    u16 h = f2bf(s);
    dh[idx] = h;
    dl[idx] = f2bf(s - bf2f(h));
}

// ---------------- scan pass 1: lane-per-d local chunk scan (all regs) ----------------
__global__ __launch_bounds__(256) void k_scan_p1(
    const float* __restrict__ xz, const u16* __restrict__ uh, const u16* __restrict__ ul,
    const float* __restrict__ xdbl, const float* __restrict__ A_log,
    float* __restrict__ HP, float* __restrict__ SS)
{
    const int d = blockIdx.x * 256 + threadIdx.x;
    const int c = blockIdx.y, b = blockIdx.z;
    const float L2E = 1.44269504088896340736f;
    f32x4 al0 = *(const f32x4*)(A_log + (size_t)d * DSTATE + 0);
    f32x4 al1 = *(const f32x4*)(A_log + (size_t)d * DSTATE + 4);
    f32x4 al2 = *(const f32x4*)(A_log + (size_t)d * DSTATE + 8);
    f32x4 al3 = *(const f32x4*)(A_log + (size_t)d * DSTATE + 12);
    f32x4 aa0, aa1, aa2, aa3;
    #pragma unroll
    for (int j = 0; j < 4; ++j) {
        aa0[j] = -__expf(al0[j]) * L2E;
        aa1[j] = -__expf(al1[j]) * L2E;
        aa2[j] = -__expf(al2[j]) * L2E;
        aa3[j] = -__expf(al3[j]) * L2E;
    }
    const int t0 = c * CHKT;
    const float* dP = xz + ((size_t)b * NT + t0) * (2 * DINNER) + d;
    const u16* uhP = uh + ((size_t)b * NT + t0) * DINNER + d;
    const u16* ulP = ul + ((size_t)b * NT + t0) * DINNER + d;
    const float* bP = xdbl + ((size_t)b * NT + t0) * 128 + DTRANK;
    f32x4 h0 = {0.f,0.f,0.f,0.f}, h1 = h0, h2 = h0, h3 = h0;
    float S = 0.f;
    float dlt = dP[0];
    float uu = bf2f(uhP[0]) + bf2f(ulP[0]);
    for (int t = 0; t < CHKT; ++t) {
        float dlt_n = 0.f, uu_n = 0.f;
        if (t + 1 < CHKT) {
            dlt_n = dP[2 * DINNER];
            uu_n = bf2f(uhP[DINNER]) + bf2f(ulP[DINNER]);
        }
        f32x4 B0 = *(const f32x4*)(bP + 0);
        f32x4 B1 = *(const f32x4*)(bP + 4);
        f32x4 B2 = *(const f32x4*)(bP + 8);
        f32x4 B3 = *(const f32x4*)(bP + 12);
        float du = dlt * uu;
        S += dlt;
        h0 = exp2v(dlt * aa0) * h0 + du * B0;
        h1 = exp2v(dlt * aa1) * h1 + du * B1;
        h2 = exp2v(dlt * aa2) * h2 + du * B2;
        h3 = exp2v(dlt * aa3) * h3 + du * B3;
        dP += 2 * DINNER; uhP += DINNER; ulP += DINNER; bP += 128;
        dlt = dlt_n; uu = uu_n;
    }
    size_t a = (((size_t)(b * NCHK + c) * DINNER) + d) * DSTATE;
    *(f32x4*)(HP + a + 0)  = h0;
    *(f32x4*)(HP + a + 4)  = h1;
    *(f32x4*)(HP + a + 8)  = h2;
    *(f32x4*)(HP + a + 12) = h3;
    SS[(size_t)(b * NCHK + c) * DINNER + d] = S;
}

// ---------------- scan pass 2: chunk-prefix; HP becomes h_init per chunk ----------------
__global__ __launch_bounds__(256) void k_scan_p2(float* __restrict__ HP,
    const float* __restrict__ SS, const float* __restrict__ A_log)
{
    int idx = blockIdx.x * 256 + threadIdx.x;
    if (idx >= NB * DINNER * DSTATE) return;
    int s = idx & (DSTATE - 1);
    int d = (idx >> 4) % DINNER;
    int b = idx / (DINNER * DSTATE);
    const float L2E = 1.44269504088896340736f;
    float aa = -__expf(A_log[d * DSTATE + s]) * L2E;
    float h = 0.f;
    #pragma unroll
    for (int c = 0; c < NCHK; ++c) {
        size_t a = (((size_t)(b * NCHK + c) * DINNER) + d) * DSTATE + s;
        float hc = HP[a];
        float P = exp2f(aa * SS[(size_t)(b * NCHK + c) * DINNER + d]);
        HP[a] = h;
        h = fmaf(P, h, hc);
    }
}

// ---------------- scan pass 3: lane-per-d chunk scan with h_init (all regs) ----------------
__global__ __launch_bounds__(256) void k_scan_p3(
    const float* __restrict__ xz,
    u16* uh, u16* ul,
    const float* __restrict__ xdbl,
    const float* __restrict__ A_log, const float* __restrict__ Dp,
    const float* __restrict__ HP)
{
    const int d = blockIdx.x * 256 + threadIdx.x;
    const int c = blockIdx.y, b = blockIdx.z;
    const float L2E = 1.44269504088896340736f;
    f32x4 al0 = *(const f32x4*)(A_log + (size_t)d * DSTATE + 0);
    f32x4 al1 = *(const f32x4*)(A_log + (size_t)d * DSTATE + 4);
    f32x4 al2 = *(const f32x4*)(A_log + (size_t)d * DSTATE + 8);
    f32x4 al3 = *(const f32x4*)(A_log + (size_t)d * DSTATE + 12);
    f32x4 aa0, aa1, aa2, aa3;
    #pragma unroll
    for (int j = 0; j < 4; ++j) {
        aa0[j] = -__expf(al0[j]) * L2E;
        aa1[j] = -__expf(al1[j]) * L2E;
        aa2[j] = -__expf(al2[j]) * L2E;
        aa3[j] = -__expf(al3[j]) * L2E;
    }
    const float dp = Dp[d];
    const int t0 = c * CHKT;
    const float* dP = xz + ((size_t)b * NT + t0) * (2 * DINNER) + d;
    const float* zP = dP + DINNER;
    const u16* uhP = uh + ((size_t)b * NT + t0) * DINNER + d;
    const u16* ulP = ul + ((size_t)b * NT + t0) * DINNER + d;
    u16* yhP = (u16*)uhP;
    u16* ylP = (u16*)ulP;
    const float* bP = xdbl + ((size_t)b * NT + t0) * 128 + DTRANK;
    size_t ha = (((size_t)(b * NCHK + c) * DINNER) + d) * DSTATE;
    f32x4 h0 = *(const f32x4*)(HP + ha + 0);
    f32x4 h1 = *(const f32x4*)(HP + ha + 4);
    f32x4 h2 = *(const f32x4*)(HP + ha + 8);
    f32x4 h3 = *(const f32x4*)(HP + ha + 12);
    float dlt = dP[0], zz = zP[0];
    float uu = bf2f(uhP[0]) + bf2f(ulP[0]);
    for (int t = 0; t < CHKT; ++t) {
        float dlt_n = 0.f, uu_n = 0.f, zz_n = 0.f;
        if (t + 1 < CHKT) {
            dlt_n = dP[2 * DINNER]; zz_n = zP[2 * DINNER];
            uu_n = bf2f(uhP[DINNER]) + bf2f(ulP[DINNER]);
        }
        f32x4 B0 = *(const f32x4*)(bP + 0);
        f32x4 B1 = *(const f32x4*)(bP + 4);
        f32x4 B2 = *(const f32x4*)(bP + 8);
        f32x4 B3 = *(const f32x4*)(bP + 12);
        f32x4 C0 = *(const f32x4*)(bP + DSTATE + 0);
        f32x4 C1 = *(const f32x4*)(bP + DSTATE + 4);
        f32x4 C2 = *(const f32x4*)(bP + DSTATE + 8);
        f32x4 C3 = *(const f32x4*)(bP + DSTATE + 12);
        float du = dlt * uu;
        h0 = exp2v(dlt * aa0) * h0 + du * B0;
        h1 = exp2v(dlt * aa1) * h1 + du * B1;
        h2 = exp2v(dlt * aa2) * h2 + du * B2;
        h3 = exp2v(dlt * aa3) * h3 + du * B3;
        f32x4 pv = h0 * C0 + h1 * C1 + h2 * C2 + h3 * C3;
        float p = (pv[0] + pv[1]) + (pv[2] + pv[3]);
        float yv = (p + uu * dp) * siluf(zz);
        u16 hh = f2bf(yv);
        yhP[0] = hh;
        ylP[0] = f2bf(yv - bf2f(hh));
        dP += 2 * DINNER; zP += 2 * DINNER;
        uhP += DINNER; ulP += DINNER; yhP += DINNER; ylP += DINNER;
        bP += 128;
        dlt = dlt_n; zz = zz_n; uu = uu_n;
    }
}

// ---------------- final fc + silu + transpose to (B,5,T) ----------------
__global__ __launch_bounds__(256) void k_fc(const float* __restrict__ hR,
    const float* __restrict__ w, const float* __restrict__ bias,
    float* __restrict__ out)
{
    int row = blockIdx.x;
    int tid = threadIdx.x;
    const float* p = hR + (size_t)row * DMODEL;
    float acc[NCLASS] = {0.f, 0.f, 0.f, 0.f, 0.f};
    #pragma unroll
    for (int j = 0; j < 6; ++j) {
        int col = tid + j * 256;
        float v = p[col];
        #pragma unroll
        for (int c = 0; c < NCLASS; ++c)
            acc[c] = fmaf(v, w[c * DMODEL + col], acc[c]);
    }
    #pragma unroll
    for (int c = 0; c < NCLASS; ++c)
        #pragma unroll
        for (int off = 1; off < 64; off <<= 1)
            acc[c] += __shfl_xor(acc[c], off);
    __shared__ float red[4][NCLASS];
    int lane = tid & 63, wv = tid >> 6;
    if (lane == 0)
        for (int c = 0; c < NCLASS; ++c) red[wv][c] = acc[c];
    __syncthreads();
    if (tid < NCLASS) {
        float s = red[0][tid] + red[1][tid] + red[2][tid] + red[3][tid] + bias[tid];
        int b = row >> 10, t = row & (NT - 1);
        out[((size_t)b * NCLASS + tid) * NT + t] = siluf(s);
    }
}

extern "C" void kernel_launch(void* const* d_in, const int* in_sizes, int n_in,
                              void* d_out, int out_size, void* d_ws, size_t ws_size,
                              hipStream_t stream)
{
    const float* x      = (const float*)d_in[0];
    const float* c1a_w  = (const float*)d_in[1];
    const float* c1a_b  = (const float*)d_in[2];
    const float* c1b_w  = (const float*)d_in[3];
    const float* c1b_b  = (const float*)d_in[4];
    const float* c1s_w  = (const float*)d_in[5];
    const float* c1s_b  = (const float*)d_in[6];
    const float* c2a_w  = (const float*)d_in[7];
    const float* c2a_b  = (const float*)d_in[8];
    const float* c2b_w  = (const float*)d_in[9];
    const float* c2b_b  = (const float*)d_in[10];
    const float* norm_w = (const float*)d_in[11];
    const float* in_w   = (const float*)d_in[12];
    const float* conv_w = (const float*)d_in[13];
    const float* conv_b = (const float*)d_in[14];
    const float* xproj_w= (const float*)d_in[15];
    const float* dt_w   = (const float*)d_in[16];
    const float* dt_b   = (const float*)d_in[17];
    const float* A_log  = (const float*)d_in[18];
    const float* Dp     = (const float*)d_in[19];
    const float* out_w  = (const float*)d_in[20];
    const float* fc_w   = (const float*)d_in[21];
    const float* fc_b   = (const float*)d_in[22];
    float* outp = (float*)d_out;
    (void)in_sizes; (void)n_in; (void)out_size; (void)ws_size;

    char* base = (char*)d_ws;
    size_t off = 0;
    auto takeB = [&](size_t bytes) { void* p = base + off; off = (off + bytes + 255) & ~(size_t)255; return p; };
    float* HCAT = (float*)takeB((size_t)NB * NDIM * NT * 4);
    float* XZ   = (float*)takeB((size_t)MROWS * 2 * DINNER * 4);
    float* RES  = (float*)takeB((size_t)MROWS * DMODEL * 4);
    u16*   XNh  = (u16*)takeB((size_t)MROWS * DMODEL * 2);
    u16*   XNl  = (u16*)takeB((size_t)MROWS * DMODEL * 2);
    u16*   Uh   = (u16*)takeB((size_t)MROWS * DINNER * 2);
    u16*   Ul   = (u16*)takeB((size_t)MROWS * DINNER * 2);
    float* XDBL = (float*)takeB((size_t)MROWS * 128 * 4);
    float* XPART= (float*)takeB((size_t)4 * MROWS * 128 * 4);
    u16*   XDh  = (u16*)takeB((size_t)MROWS * 128 * 2);
    u16*   XDl  = (u16*)takeB((size_t)MROWS * 128 * 2);
    u16*   Wh   = (u16*)takeB((size_t)9437184 * 2);
    u16*   Wl   = (u16*)takeB((size_t)9437184 * 2);
    u16*   DTh  = (u16*)takeB((size_t)DINNER * 128 * 2);
    u16*   DTl  = (u16*)takeB((size_t)DINNER * 128 * 2);
    float* HP   = (float*)takeB((size_t)NB * NCHK * DINNER * DSTATE * 4);
    float* SS   = (float*)takeB((size_t)NB * NCHK * DINNER * 4);
    u16*   CW1h = (u16*)takeB(18432);
    u16*   CW1l = (u16*)takeB(18432);
    u16*   CW2h = (u16*)takeB(18432);
    u16*   CW2l = (u16*)takeB(18432);
    u16*   CW3h = (u16*)takeB(18432);
    u16*   CW3l = (u16*)takeB(18432);
    u16*   ZPAD = (u16*)takeB(256);

    u16* T1h = (u16*)XZ;
    u16* T1l = T1h + (size_t)NB * NDIM * NT * 32;
    u16* T3h = (u16*)XZ;
    u16* T3l = T3h + (size_t)NB * NDIM * NT * 32;
    u16* P1h = Uh;
    u16* P1l = Ul;

    const int n1 = NB * NDIM * NT;
    k_prep  <<<(n1 + 255) / 256, 256, 0, stream>>>(x, HCAT, ZPAD);
    k_wconv3<<<dim3(36, 3), 256, 0, stream>>>(c1b_w, CW1h, CW1l,
                                              c2a_w, CW2h, CW2l,
                                              c2b_w, CW3h, CW3l);
    k_conv1a<<<(n1 + 255) / 256, 256, 0, stream>>>(HCAT, c1a_w, c1a_b, T1h, T1l);
    k_convmfma<0><<<dim3(16, 96, NB), 256, 0, stream>>>(
        T1h, T1l, CW1h, CW1l, HCAT, c1s_w, c1s_b, nullptr, nullptr,
        c1b_b, P1h, P1l, nullptr, ZPAD);
    k_convmfma<1><<<dim3(16, 48, NB), 256, 0, stream>>>(
        P1h, P1l, CW2h, CW2l, nullptr, nullptr, nullptr, nullptr, nullptr,
        c2a_b, T3h, T3l, nullptr, ZPAD);
    k_convmfma<2><<<dim3(16, 48, NB), 256, 0, stream>>>(
        T3h, T3l, CW3h, CW3l, nullptr, nullptr, nullptr, P1h, P1l,
        c2b_b, nullptr, nullptr, RES, ZPAD);

    for (int l = 0; l < NLAYER; ++l) {
        k_rmsnorm<<<MROWS, 256, 0, stream>>>(RES, norm_w + (size_t)l * DMODEL, XNh, XNl);
        k_split<<<(9437184 / 4 + 255) / 256, 256, 0, stream>>>(
            in_w + (size_t)l * 2 * DINNER * DMODEL, Wh, Wl, 9437184 / 4);
        k_gemm256<0, 256, 0><<<dim3(2 * DINNER / 256, MROWS / 256), 512, 0, stream>>>(
            XNh, XNl, DMODEL, Wh, Wl, DMODEL, XZ, 2 * DINNER, DMODEL);
        k_conv1d<<<dim3(DINNER / 512, NT / 16, NB), 256, 0, stream>>>(
            XZ, conv_w + (size_t)l * DINNER * 4, conv_b + (size_t)l * DINNER, Uh, Ul);
        k_wsplit2<<<(98304 + DINNER * 128 + 255) / 256, 256, 0, stream>>>(
            xproj_w + (size_t)l * 128 * DINNER, Wh, Wl,
            dt_w + (size_t)l * DINNER * DTRANK, DTh, DTl);
        k_gemm_mfma<0><<<dim3(1, MROWS / 128, 4), 256, 0, stream>>>(
            Uh, Ul, DINNER, Wh, Wl, DINNER, XPART, 128, DINNER, nullptr, (size_t)MROWS * 128);
        k_reduce_split<<<(MROWS * 128 + 255) / 256, 256, 0, stream>>>(XPART, XDBL, XDh, XDl);
        k_gemm_mfma<1><<<dim3(DINNER / 128, MROWS / 128, 1), 256, 0, stream>>>(
            XDh, XDl, 128, DTh, DTl, 128, XZ, 2 * DINNER, 128,
            dt_b + (size_t)l * DINNER, 0);
        k_scan_p1<<<dim3(DINNER / 256, NCHK, NB), 256, 0, stream>>>(
            XZ, Uh, Ul, XDBL, A_log + (size_t)l * DINNER * DSTATE, HP, SS);
        k_scan_p2<<<(NB * DINNER * DSTATE + 255) / 256, 256, 0, stream>>>(
            HP, SS, A_log + (size_t)l * DINNER * DSTATE);
        k_scan_p3<<<dim3(DINNER / 256, NCHK, NB), 256, 0, stream>>>(
            XZ, Uh, Ul, XDBL, A_log + (size_t)l * DINNER * DSTATE,
            Dp + (size_t)l * DINNER, HP);
        k_split<<<(4718592 / 4 + 255) / 256, 256, 0, stream>>>(
            out_w + (size_t)l * DMODEL * DINNER, Wh, Wl, 4718592 / 4);
        k_gemm256<2, 192, 1><<<dim3(DMODEL / 192, MROWS / 256), 512, 0, stream>>>(
            Uh, Ul, DINNER, Wh, Wl, DINNER, RES, DMODEL, DINNER);
    }
    k_fc<<<MROWS, 256, 0, stream>>>(RES, fc_w, fc_b, outp);
}

// Round 17
// 4519.420 us; speedup vs baseline: 1.0310x; 1.0109x over previous
//
#include <hip/hip_runtime.h>
#include <cstdint>
#include <cstddef>

#define DEV static __device__ __forceinline__

typedef unsigned short u16;
typedef unsigned int   u32;
typedef __bf16 bf16x8 __attribute__((ext_vector_type(8)));
typedef float  f32x4  __attribute__((ext_vector_type(4)));

namespace {
constexpr int NB     = 8;
constexpr int NT     = 1024;
constexpr int NMEL   = 96;
constexpr int NDIM   = 192;
constexpr int NCH    = 32;
constexpr int DMODEL = 1536;
constexpr int DINNER = 3072;
constexpr int DSTATE = 16;
constexpr int DTRANK = 96;
constexpr int NLAYER = 4;
constexpr int NCLASS = 5;
constexpr int MROWS  = NB * NT;   // 8192
constexpr int NCHK   = 16;
constexpr int CHKT   = NT / NCHK; // 64
}

DEV float siluf(float x)    { return x / (1.0f + __expf(-x)); }
DEV float softplusf(float x){ return fmaxf(x, 0.0f) + log1pf(__expf(-fabsf(x))); }

DEV u16 f2bf(float f) {
    u32 u = __float_as_uint(f);
    u32 r = u + 0x7FFFu + ((u >> 16) & 1u);
    return (u16)(r >> 16);
}
DEV float bf2f(u16 h) { return __uint_as_float(((u32)h) << 16); }

DEV f32x4 exp2v(f32x4 x) {
    f32x4 r;
    r[0] = exp2f(x[0]); r[1] = exp2f(x[1]);
    r[2] = exp2f(x[2]); r[3] = exp2f(x[3]);
    return r;
}

#define GLD(gp, lp) __builtin_amdgcn_global_load_lds( \
    (const __attribute__((address_space(1))) u32*)(const void*)(gp), \
    (__attribute__((address_space(3))) u32*)(void*)(lp), 16, 0, 0)

// ---------------- prep: x -> hcat (B,192,T): [x ; relu(diff)]; also zero ZPAD ----------------
__global__ __launch_bounds__(256) void k_prep(const float* __restrict__ x,
                                              float* __restrict__ hcat,
                                              u16* __restrict__ zpad)
{
    if (blockIdx.x == 0 && threadIdx.x < 128) zpad[threadIdx.x] = 0;
    int idx = blockIdx.x * 256 + threadIdx.x;
    if (idx >= NB * NDIM * NT) return;
    int t = idx & (NT - 1);
    int m = (idx >> 10) % NDIM;
    int b = idx / (NDIM * NT);
    float v;
    if (m < NMEL) {
        v = x[((size_t)b * NMEL + m) * NT + t];
    } else {
        int mm = m - NMEL;
        v = 0.f;
        if (t > 0) {
            const float* p = x + ((size_t)b * NMEL + mm) * NT + t;
            v = fmaxf(p[0] - p[-1], 0.f);
        }
    }
    hcat[idx] = v;
}

// ---------------- conv weight prep x3: (32,32,3,3) -> [tap][cout][ci] hi/lo ----------------
__global__ __launch_bounds__(256) void k_wconv3(
    const float* __restrict__ w0, u16* __restrict__ dh0, u16* __restrict__ dl0,
    const float* __restrict__ w1, u16* __restrict__ dh1, u16* __restrict__ dl1,
    const float* __restrict__ w2, u16* __restrict__ dh2, u16* __restrict__ dl2)
{
    int idx = blockIdx.x * 256 + threadIdx.x;
    if (idx >= 9216) return;
    const float* w = (blockIdx.y == 0) ? w0 : (blockIdx.y == 1) ? w1 : w2;
    u16* dh = (blockIdx.y == 0) ? dh0 : (blockIdx.y == 1) ? dh1 : dh2;
    u16* dl = (blockIdx.y == 0) ? dl0 : (blockIdx.y == 1) ? dl1 : dl2;
    int ci = idx & 31, cout = (idx >> 5) & 31, tap = idx >> 10;
    float v = w[((size_t)cout * 32 + ci) * 9 + tap];
    u16 h = f2bf(v);
    dh[idx] = h;
    dl[idx] = f2bf(v - bf2f(h));
}

// ---------------- conv1a (1->32, 3x3) + silu -> NHWC bf16 hi/lo ----------------
__global__ __launch_bounds__(256) void k_conv1a(const float* __restrict__ hcat,
    const float* __restrict__ w, const float* __restrict__ bias,
    u16* __restrict__ oh, u16* __restrict__ ol)   // (B,192,T,32)
{
    int idx = blockIdx.x * 256 + threadIdx.x;
    if (idx >= NB * NDIM * NT) return;
    int t = idx & (NT - 1);
    int h = (idx >> 10) % NDIM;
    int b = idx / (NDIM * NT);
    float in[3][3];
    #pragma unroll
    for (int dh = 0; dh < 3; ++dh)
        #pragma unroll
        for (int dw = 0; dw < 3; ++dw) {
            int hh = h + dh - 1, tt = t + dw - 1;
            in[dh][dw] = (hh >= 0 && hh < NDIM && tt >= 0 && tt < NT)
                       ? hcat[((size_t)b * NDIM + hh) * NT + tt] : 0.f;
        }
    u16 hb[32], lb[32];
    #pragma unroll
    for (int c = 0; c < NCH; ++c) {
        float acc = bias[c];
        #pragma unroll
        for (int dh = 0; dh < 3; ++dh)
            #pragma unroll
            for (int dw = 0; dw < 3; ++dw)
                acc = fmaf(in[dh][dw], w[c * 9 + dh * 3 + dw], acc);
        float o = siluf(acc);
        u16 hh2 = f2bf(o);
        hb[c] = hh2;
        lb[c] = f2bf(o - bf2f(hh2));
    }
    size_t ob = (((size_t)b * NDIM + h) * NT + t) * 32;
    #pragma unroll
    for (int j = 0; j < 8; ++j) {
        ushort4 hv = { hb[j*4], hb[j*4+1], hb[j*4+2], hb[j*4+3] };
        ushort4 lv = { lb[j*4], lb[j*4+1], lb[j*4+2], lb[j*4+3] };
        *(ushort4*)(oh + ob + j * 4) = hv;
        *(ushort4*)(ol + ob + j * 4) = lv;
    }
}

// ---------------- MFMA implicit-GEMM conv 32->32 3x3 (NHWC bf16 hi/lo) ----------------
template<int VAR>
__global__ __launch_bounds__(256) void k_convmfma(
    const u16* __restrict__ Xh, const u16* __restrict__ Xl,
    const u16* __restrict__ CWh, const u16* __restrict__ CWl,
    const float* __restrict__ hcat, const float* __restrict__ sw, const float* __restrict__ sb,
    const u16* __restrict__ Sh, const u16* __restrict__ Sl,
    const float* __restrict__ bias,
    u16* __restrict__ Oh, u16* __restrict__ Ol,
    float* __restrict__ RES,
    const u16* __restrict__ zeropad)
{
    constexpr int HIN = (VAR == 0) ? 192 : 96;
    __shared__ __align__(16) u16 lds[2][8448];
    const int t0 = blockIdx.x * 64;
    const int ho = blockIdx.y;
    const int b  = blockIdx.z;
    const int tid = threadIdx.x;
    const int wid = tid >> 6, lane = tid & 63;
    const int r0 = 2 * ho - 1;

    for (int cb = wid * 64; cb < 2112; cb += 256) {
        int c = cb + lane;
        int plane = (c >= 1056) ? 1 : 0;
        int cc = c - plane * 1056;
        int row = cc / 264;
        int rc  = cc - row * 264;
        int pos = rc >> 2;
        int slot = rc & 3;
        int cib = slot ^ ((pos >> 1) & 3);
        int h = r0 + row;
        int t = t0 - 1 + pos;
        const u16* bp = plane ? Xl : Xh;
        const u16* src = (h >= 0 && h < HIN && t >= 0 && t < NT)
            ? bp + (((size_t)(b * HIN + h)) * NT + t) * 32 + cib * 8
            : zeropad;
        u16* ldst = &lds[0][0] + (size_t)cb * 8;
        GLD(src, ldst);
    }
    __syncthreads();

    const int fr = lane & 15, fq = lane >> 4;
    f32x4 acc[2][2];
    #pragma unroll
    for (int pr = 0; pr < 2; ++pr)
        #pragma unroll
        for (int mt = 0; mt < 2; ++mt) acc[pr][mt] = (f32x4){0.f, 0.f, 0.f, 0.f};

    #pragma unroll
    for (int dh = 0; dh < 3; ++dh) {
        #pragma unroll
        for (int dt = 0; dt < 3; ++dt) {
            int tap = dh * 3 + dt;
            bf16x8 wh[2], wl[2];
            #pragma unroll
            for (int mt = 0; mt < 2; ++mt) {
                size_t wo = ((size_t)tap * 32 + mt * 16 + fr) * 32 + fq * 8;
                wh[mt] = *(const bf16x8*)(CWh + wo);
                wl[mt] = *(const bf16x8*)(CWl + wo);
            }
            int p = (wid << 4) + fr + dt;
            int sl = fq ^ ((p >> 1) & 3);
            #pragma unroll
            for (int pr = 0; pr < 2; ++pr) {
                int rr = pr + dh;
                const u16* lp = &lds[0][0] + ((rr * 66 + p) * 4 + sl) * 8;
                bf16x8 xh = *(const bf16x8*)lp;
                bf16x8 xl = *(const bf16x8*)(lp + 8448);
                #pragma unroll
                for (int mt = 0; mt < 2; ++mt) {
                    acc[pr][mt] = __builtin_amdgcn_mfma_f32_16x16x32_bf16(wh[mt], xh, acc[pr][mt], 0, 0, 0);
                    acc[pr][mt] = __builtin_amdgcn_mfma_f32_16x16x32_bf16(wh[mt], xl, acc[pr][mt], 0, 0, 0);
                    acc[pr][mt] = __builtin_amdgcn_mfma_f32_16x16x32_bf16(wl[mt], xh, acc[pr][mt], 0, 0, 0);
                }
            }
        }
    }

    const int t = t0 + (wid << 4) + fr;
    float hc0 = 0.f, hc1 = 0.f;
    if (VAR == 0) {
        hc0 = hcat[((size_t)(b * NDIM + 2 * ho    )) * NT + t];
        hc1 = hcat[((size_t)(b * NDIM + 2 * ho + 1)) * NT + t];
    }
    #pragma unroll
    for (int mt = 0; mt < 2; ++mt) {
        float v0[4], v1[4];
        if (VAR == 2) {
            ushort4 s0h = *(const ushort4*)(Sh + (((size_t)(b * 96 + 2 * ho    )) * NT + t) * 32 + mt * 16 + fq * 4);
            ushort4 s0l = *(const ushort4*)(Sl + (((size_t)(b * 96 + 2 * ho    )) * NT + t) * 32 + mt * 16 + fq * 4);
            ushort4 s1h = *(const ushort4*)(Sh + (((size_t)(b * 96 + 2 * ho + 1)) * NT + t) * 32 + mt * 16 + fq * 4);
            ushort4 s1l = *(const ushort4*)(Sl + (((size_t)(b * 96 + 2 * ho + 1)) * NT + t) * 32 + mt * 16 + fq * 4);
            v0[0] = bf2f(s0h.x) + bf2f(s0l.x); v0[1] = bf2f(s0h.y) + bf2f(s0l.y);
            v0[2] = bf2f(s0h.z) + bf2f(s0l.z); v0[3] = bf2f(s0h.w) + bf2f(s0l.w);
            v1[0] = bf2f(s1h.x) + bf2f(s1l.x); v1[1] = bf2f(s1h.y) + bf2f(s1l.y);
            v1[2] = bf2f(s1h.z) + bf2f(s1l.z); v1[3] = bf2f(s1h.w) + bf2f(s1l.w);
        }
        u16 hs[4], ls[4];
        float r0v[4], r1v[4];
        #pragma unroll
        for (int r = 0; r < 4; ++r) {
            int c = mt * 16 + fq * 4 + r;
            float a0 = acc[0][mt][r] + bias[c];
            float a1 = acc[1][mt][r] + bias[c];
            if (VAR == 0) {
                a0 += fmaf(hc0, sw[c], sb[c]);
                a1 += fmaf(hc1, sw[c], sb[c]);
            }
            if (VAR == 2) { a0 += v0[r]; a1 += v1[r]; }
            a0 = siluf(a0); a1 = siluf(a1);
            if (VAR == 1) { r0v[r] = a0; r1v[r] = a1; }
            else {
                float m = fmaxf(a0, a1);
                if (VAR == 2) r0v[r] = m;
                else { u16 hh = f2bf(m); hs[r] = hh; ls[r] = f2bf(m - bf2f(hh)); }
            }
        }
        if (VAR == 0) {
            size_t ob = (((size_t)(b * 96 + ho)) * NT + t) * 32 + mt * 16 + fq * 4;
            ushort4 hv = { hs[0], hs[1], hs[2], hs[3] };
            ushort4 lv = { ls[0], ls[1], ls[2], ls[3] };
            *(ushort4*)(Oh + ob) = hv;
            *(ushort4*)(Ol + ob) = lv;
        } else if (VAR == 1) {
            #pragma unroll
            for (int pr = 0; pr < 2; ++pr) {
                size_t ob = (((size_t)(b * 96 + 2 * ho + pr)) * NT + t) * 32 + mt * 16 + fq * 4;
                u16 hh[4], ll[4];
                #pragma unroll
                for (int r = 0; r < 4; ++r) {
                    float m = pr ? r1v[r] : r0v[r];
                    hh[r] = f2bf(m); ll[r] = f2bf(m - bf2f(hh[r]));
                }
                ushort4 hv = { hh[0], hh[1], hh[2], hh[3] };
                ushort4 lv = { ll[0], ll[1], ll[2], ll[3] };
                *(ushort4*)(Oh + ob) = hv;
                *(ushort4*)(Ol + ob) = lv;
            }
        } else {
            #pragma unroll
            for (int r = 0; r < 4; ++r) {
                int c = mt * 16 + fq * 4 + r;
                RES[((size_t)b * NT + t) * DMODEL + c * 48 + ho] = r0v[r];
            }
        }
    }
}

// ---------------- stitched: rmsnorm (blocks [0,MROWS)) + in_w split (rest) ----------------
__global__ __launch_bounds__(256) void k_norm_insplit(const float* __restrict__ in,
    const float* __restrict__ w, u16* __restrict__ oh, u16* __restrict__ ol,
    const float* __restrict__ wsrc, u16* __restrict__ dh, u16* __restrict__ dl)
{
    int tid = threadIdx.x;
    if (blockIdx.x >= MROWS) {
        int idx = (blockIdx.x - MROWS) * 256 + tid;
        if (idx >= 9437184 / 4) return;
        float4 v = ((const float4*)wsrc)[idx];
        u16 h0 = f2bf(v.x), h1 = f2bf(v.y), h2 = f2bf(v.z), h3 = f2bf(v.w);
        u16 l0 = f2bf(v.x - bf2f(h0)), l1 = f2bf(v.y - bf2f(h1));
        u16 l2 = f2bf(v.z - bf2f(h2)), l3 = f2bf(v.w - bf2f(h3));
        uint2 hv = { (u32)h0 | ((u32)h1 << 16), (u32)h2 | ((u32)h3 << 16) };
        uint2 lv = { (u32)l0 | ((u32)l1 << 16), (u32)l2 | ((u32)l3 << 16) };
        ((uint2*)dh)[idx] = hv;
        ((uint2*)dl)[idx] = lv;
        return;
    }
    int row = blockIdx.x;
    const float* p = in + (size_t)row * DMODEL;
    float v[6]; float ss = 0.f;
    #pragma unroll
    for (int j = 0; j < 6; ++j) { v[j] = p[tid + j * 256]; ss = fmaf(v[j], v[j], ss); }
    #pragma unroll
    for (int off = 1; off < 64; off <<= 1) ss += __shfl_xor(ss, off);
    __shared__ float red[4];
    int lane = tid & 63, wv = tid >> 6;
    if (lane == 0) red[wv] = ss;
    __syncthreads();
    float tot = red[0] + red[1] + red[2] + red[3];
    float sc = rsqrtf(tot * (1.0f / DMODEL) + 1e-5f);
    #pragma unroll
    for (int j = 0; j < 6; ++j) {
        int col = tid + j * 256;
        float xv = v[j] * sc * w[col];
        u16 h = f2bf(xv);
        oh[(size_t)row * DMODEL + col] = h;
        ol[(size_t)row * DMODEL + col] = f2bf(xv - bf2f(h));
    }
}

// ---------------- stitched: conv1d (blocks [0,3072)) + xproj/dt weight split ----------------
__global__ __launch_bounds__(256) void k_conv1d_wsplit(
    const float* __restrict__ xz, const float* __restrict__ w,
    const float* __restrict__ bias, u16* __restrict__ uh, u16* __restrict__ ul,
    const float* __restrict__ xpw, u16* __restrict__ xh, u16* __restrict__ xl,
    const float* __restrict__ dtw, u16* __restrict__ dh, u16* __restrict__ dl)
{
    constexpr int CT = 16;
    const int tid = threadIdx.x;
    if (blockIdx.x >= 3072) {
        int idx = (blockIdx.x - 3072) * 256 + tid;
        if (idx < 98304) {
            float4 v = ((const float4*)xpw)[idx];
            u16 h0 = f2bf(v.x), h1 = f2bf(v.y), h2 = f2bf(v.z), h3 = f2bf(v.w);
            u16 l0 = f2bf(v.x - bf2f(h0)), l1 = f2bf(v.y - bf2f(h1));
            u16 l2 = f2bf(v.z - bf2f(h2)), l3 = f2bf(v.w - bf2f(h3));
            uint2 hv = { (u32)h0 | ((u32)h1 << 16), (u32)h2 | ((u32)h3 << 16) };
            uint2 lv = { (u32)l0 | ((u32)l1 << 16), (u32)l2 | ((u32)l3 << 16) };
            ((uint2*)xh)[idx] = hv;
            ((uint2*)xl)[idx] = lv;
            return;
        }
        int j = idx - 98304;
        if (j >= DINNER * 128) return;
        int col = j & 127, row = j >> 7;
        float v = (col < DTRANK) ? dtw[(size_t)row * DTRANK + col] : 0.f;
        u16 h = f2bf(v);
        dh[j] = h;
        dl[j] = f2bf(v - bf2f(h));
        return;
    }
    const int xb = blockIdx.x;
    const int d  = ((xb % 6) * 256 + tid) * 2;
    const int t0 = ((xb / 6) % 64) * CT;
    const int b  = xb / 384;
    float4 w0 = *(const float4*)(w + (size_t)d * 4);
    float4 w1 = *(const float4*)(w + (size_t)(d + 1) * 4);
    float2 bb = *(const float2*)(bias + d);
    const float* xp = xz + ((size_t)b * NT + t0) * (2 * DINNER) + d;
    float2 a0 = {0.f, 0.f}, a1 = {0.f, 0.f}, a2 = {0.f, 0.f};
    if (t0 > 0) {
        a0 = *(const float2*)(xp - 3 * 2 * DINNER);
        a1 = *(const float2*)(xp - 2 * 2 * DINNER);
        a2 = *(const float2*)(xp - 1 * 2 * DINNER);
    }
    u32* uhp = (u32*)(uh + ((size_t)b * NT + t0) * DINNER + d);
    u32* ulp = (u32*)(ul + ((size_t)b * NT + t0) * DINNER + d);
    #pragma unroll
    for (int t = 0; t < CT; ++t) {
        float2 a3 = *(const float2*)(xp + (size_t)t * 2 * DINNER);
        float o0 = siluf(bb.x + a0.x * w0.x + a1.x * w0.y + a2.x * w0.z + a3.x * w0.w);
        float o1 = siluf(bb.y + a0.y * w1.x + a1.y * w1.y + a2.y * w1.z + a3.y * w1.w);
        u16 h0 = f2bf(o0), h1 = f2bf(o1);
        u16 l0 = f2bf(o0 - bf2f(h0)), l1 = f2bf(o1 - bf2f(h1));
        uhp[(size_t)t * (DINNER / 2)] = (u32)h0 | ((u32)h1 << 16);
        ulp[(size_t)t * (DINNER / 2)] = (u32)l0 | ((u32)l1 << 16);
        a0 = a1; a1 = a2; a2 = a3;
    }
}

// ---------------- 128x128 MFMA GEMM (BK=64) for dt / x_proj ----------------
template<int EPI>
__global__ __launch_bounds__(256) void k_gemm_mfma(
    const u16* __restrict__ Ahi, const u16* __restrict__ Alo, int lda,
    const u16* __restrict__ Bhi, const u16* __restrict__ Blo, int ldb,
    float* __restrict__ C, int ldc, int Ktot,
    const float* __restrict__ bias, size_t zStride)
{
    __shared__ __align__(16) u16 lds[4][8192];
    const int tid = threadIdx.x;
    const int m0 = blockIdx.y * 128, n0 = blockIdx.x * 128;
    const int kPer = Ktot / gridDim.z;
    const int kBase = blockIdx.z * kPer;
    const int wid = tid >> 6, lane = tid & 63;
    const int wr = wid >> 1, wc = wid & 1;
    const int fr = lane & 15, fq = lane >> 4;
    const int srow  = tid >> 3;
    const int sslot = (tid & 7) ^ ((tid >> 3) & 7);

    f32x4 acc[4][4];
    #pragma unroll
    for (int mi = 0; mi < 4; ++mi)
        #pragma unroll
        for (int ni = 0; ni < 4; ++ni) acc[mi][ni] = (f32x4){0.f, 0.f, 0.f, 0.f};

    for (int k0 = kBase; k0 < kBase + kPer; k0 += 64) {
        #pragma unroll
        for (int i = 0; i < 4; ++i) {
            int row = i * 32 + srow;
            size_t offA = (size_t)(m0 + row) * lda + k0 + sslot * 8;
            size_t offB = (size_t)(n0 + row) * ldb + k0 + sslot * 8;
            u16* lb = &lds[0][0] + i * 2048 + (wid << 9);
            GLD(Ahi + offA, lb);
            GLD(Alo + offA, lb + 8192);
            GLD(Bhi + offB, lb + 16384);
            GLD(Blo + offB, lb + 24576);
        }
        __syncthreads();
        #pragma unroll
        for (int h = 0; h < 2; ++h) {
            bf16x8 ah[4], al[4], bh[4], bl[4];
            #pragma unroll
            for (int mi = 0; mi < 4; ++mi) {
                int row = wr * 64 + mi * 16 + fr;
                int sl  = (h * 4 + fq) ^ (row & 7);
                const u16* p = &lds[0][row * 64 + sl * 8];
                ah[mi] = *(const bf16x8*)p;
                al[mi] = *(const bf16x8*)(p + 8192);
            }
            #pragma unroll
            for (int ni = 0; ni < 4; ++ni) {
                int row = wc * 64 + ni * 16 + fr;
                int sl  = (h * 4 + fq) ^ (row & 7);
                const u16* p = &lds[2][row * 64 + sl * 8];
                bh[ni] = *(const bf16x8*)p;
                bl[ni] = *(const bf16x8*)(p + 8192);
            }
            #pragma unroll
            for (int mi = 0; mi < 4; ++mi)
                #pragma unroll
                for (int ni = 0; ni < 4; ++ni) {
                    acc[mi][ni] = __builtin_amdgcn_mfma_f32_16x16x32_bf16(ah[mi], bh[ni], acc[mi][ni], 0, 0, 0);
                    acc[mi][ni] = __builtin_amdgcn_mfma_f32_16x16x32_bf16(ah[mi], bl[ni], acc[mi][ni], 0, 0, 0);
                    acc[mi][ni] = __builtin_amdgcn_mfma_f32_16x16x32_bf16(al[mi], bh[ni], acc[mi][ni], 0, 0, 0);
                }
        }
        __syncthreads();
    }

    float* Cz = C + (EPI == 0 ? (size_t)blockIdx.z * zStride : (size_t)0);
    #pragma unroll
    for (int mi = 0; mi < 4; ++mi)
        #pragma unroll
        for (int ni = 0; ni < 4; ++ni) {
            int gr = m0 + wr * 64 + mi * 16 + fq * 4;
            int gc = n0 + wc * 64 + ni * 16 + fr;
            float* cp = Cz + (size_t)gr * ldc + gc;
            #pragma unroll
            for (int r = 0; r < 4; ++r) {
                float v = acc[mi][ni][r];
                if (EPI == 1) v = softplusf(v + bias[gc]);
                if (EPI == 2) v += cp[(size_t)r * ldc];
                cp[(size_t)r * ldc] = v;
            }
        }
}

// ---------------- 256xBN deep-phased MFMA GEMM (BK=32, 8 waves, free-run) ----------------
template<int EPI, int BN, int SWZ>
__global__ __launch_bounds__(512, 2) void k_gemm256(
    const u16* __restrict__ Ahi, const u16* __restrict__ Alo, int lda,
    const u16* __restrict__ Bhi, const u16* __restrict__ Blo, int ldb,
    float* __restrict__ C, int ldc, int Ktot)
{
    constexpr int BM = 256;
    constexpr int TILE = (2 * BM + 2 * BN) * 64;       // bytes per K-tile
    constexpr int NUNITS = TILE / 8192;
    constexpr int NI = BN / 64;                        // ni tiles per wave
    __shared__ __align__(16) u16 lds[2 * TILE / 2];
    const int tid = threadIdx.x;
    int m0, n0;
    if (SWZ) {
        const int nwg = gridDim.x * gridDim.y;
        const int lin = blockIdx.y * gridDim.x + blockIdx.x;
        const int swz = (lin & 7) * (nwg >> 3) + (lin >> 3);
        m0 = (swz / gridDim.x) * BM;
        n0 = (swz % gridDim.x) * BN;
    } else {
        m0 = blockIdx.y * BM;
        n0 = blockIdx.x * BN;
    }
    const int wid = tid >> 6, lane = tid & 63;
    const int wr = wid >> 2, wc = wid & 3;             // 2 x 4 waves
    const int fr = lane & 15, fq = lane >> 4;
    const int nK = Ktot / 32;

    auto STAGE = [&](int buf, int k0, int u) {
        int goff = u * 8192 + tid * 16;                // byte in packed tile
        int plane, rb;
        if (goff < BM * 64)                 { plane = 0; rb = goff; }
        else if (goff < 2 * BM * 64)        { plane = 1; rb = goff - BM * 64; }
        else if (goff < 2 * BM * 64 + BN * 64) { plane = 2; rb = goff - 2 * BM * 64; }
        else                                { plane = 3; rb = goff - 2 * BM * 64 - BN * 64; }
        int row  = rb >> 6;
        int slot = (rb >> 4) & 3;
        int ss   = slot ^ ((row >> 1) & 3);
        const u16* gp;
        if (plane == 0)      gp = Ahi + (size_t)(m0 + row) * lda + k0 + ss * 8;
        else if (plane == 1) gp = Alo + (size_t)(m0 + row) * lda + k0 + ss * 8;
        else if (plane == 2) gp = Bhi + (size_t)(n0 + row) * ldb + k0 + ss * 8;
        else                 gp = Blo + (size_t)(n0 + row) * ldb + k0 + ss * 8;
        u16* ldst = lds + ((size_t)buf * TILE + (size_t)u * 8192 + (size_t)wid * 1024) / 2;
        GLD(gp, ldst);
    };

    f32x4 acc[8][NI];
    #pragma unroll
    for (int mi = 0; mi < 8; ++mi)
        #pragma unroll
        for (int ni = 0; ni < NI; ++ni) acc[mi][ni] = (f32x4){0.f, 0.f, 0.f, 0.f};

    #pragma unroll
    for (int u = 0; u < NUNITS; ++u) STAGE(0, 0, u);

    for (int kt = 0; kt < nK; ++kt) {
        const int cur = kt & 1;
        __syncthreads();
        const int k1 = (kt + 1) * 32;
        const bool pf = (kt + 1 < nK);
        bf16x8 bh[NI], bl[NI];
        #pragma unroll
        for (int ni = 0; ni < NI; ++ni) {
            int row = wc * (BN / 4) + ni * 16 + fr;
            int sl  = fq ^ ((row >> 1) & 3);
            const u16* p = lds + ((size_t)cur * TILE + 2 * BM * 64 + (size_t)row * 64 + (size_t)sl * 16) / 2;
            bh[ni] = *(const bf16x8*)p;
            bl[ni] = *(const bf16x8*)(p + BN * 32);
        }
        #pragma unroll
        for (int q = 0; q < 4; ++q) {
            if (q < 2 && pf) {
                #pragma unroll
                for (int u = (q * NUNITS) / 2; u < ((q + 1) * NUNITS) / 2; ++u)
                    STAGE(cur ^ 1, k1, u);
            }
            bf16x8 ah[2], al[2];
            #pragma unroll
            for (int j = 0; j < 2; ++j) {
                int row = wr * 128 + (2 * q + j) * 16 + fr;
                int sl  = fq ^ ((row >> 1) & 3);
                const u16* p = lds + ((size_t)cur * TILE + (size_t)row * 64 + (size_t)sl * 16) / 2;
                ah[j] = *(const bf16x8*)p;
                al[j] = *(const bf16x8*)(p + BM * 32);
            }
            __builtin_amdgcn_s_setprio(1);
            #pragma unroll
            for (int j = 0; j < 2; ++j)
                #pragma unroll
                for (int ni = 0; ni < NI; ++ni) {
                    acc[2 * q + j][ni] = __builtin_amdgcn_mfma_f32_16x16x32_bf16(ah[j], bh[ni], acc[2 * q + j][ni], 0, 0, 0);
                    acc[2 * q + j][ni] = __builtin_amdgcn_mfma_f32_16x16x32_bf16(ah[j], bl[ni], acc[2 * q + j][ni], 0, 0, 0);
                    acc[2 * q + j][ni] = __builtin_amdgcn_mfma_f32_16x16x32_bf16(al[j], bh[ni], acc[2 * q + j][ni], 0, 0, 0);
                }
            __builtin_amdgcn_s_setprio(0);
        }
    }

    #pragma unroll
    for (int mi = 0; mi < 8; ++mi)
        #pragma unroll
        for (int ni = 0; ni < NI; ++ni) {
            int gr = m0 + wr * 128 + mi * 16 + fq * 4;
            int gc = n0 + wc * (BN / 4) + ni * 16 + fr;
            float* cp = C + (size_t)gr * ldc + gc;
            #pragma unroll
            for (int r = 0; r < 4; ++r) {
                float v = acc[mi][ni][r];
                if (EPI == 2) v += cp[(size_t)r * ldc];
                cp[(size_t)r * ldc] = v;
            }
        }
}

// ---------------- reduce 4 split-K slabs of x_proj + split to hi/lo ----------------
__global__ __launch_bounds__(256) void k_reduce_split(const float* __restrict__ part,
    float* __restrict__ out, u16* __restrict__ dh, u16* __restrict__ dl)
{
    int idx = blockIdx.x * 256 + threadIdx.x;
    if (idx >= MROWS * 128) return;
    float s = part[idx] + part[(size_t)1 * MROWS * 128 + idx]
            + part[(size_t)2 * MROWS * 128 + idx] + part[(size_t)3 * MROWS * 128 + idx];
    out[idx] = s;
    u16 h = f2bf(s);
    dh[idx] = h;
    dl[idx] = f2bf(s - bf2f(h));
}

// ---------------- scan pass 1: lane-per-d local chunk scan (all regs) ----------------
__global__ __launch_bounds__(256) void k_scan_p1(
    const float* __restrict__ xz, const u16* __restrict__ uh, const u16* __restrict__ ul,
    const float* __restrict__ xdbl, const float* __restrict__ A_log,
    float* __restrict__ HP, float* __restrict__ SS)
{
    const int d = blockIdx.x * 256 + threadIdx.x;
    const int c = blockIdx.y, b = blockIdx.z;
    const float L2E = 1.44269504088896340736f;
    f32x4 al0 = *(const f32x4*)(A_log + (size_t)d * DSTATE + 0);
    f32x4 al1 = *(const f32x4*)(A_log + (size_t)d * DSTATE + 4);
    f32x4 al2 = *(const f32x4*)(A_log + (size_t)d * DSTATE + 8);
    f32x4 al3 = *(const f32x4*)(A_log + (size_t)d * DSTATE + 12);
    f32x4 aa0, aa1, aa2, aa3;
    #pragma unroll
    for (int j = 0; j < 4; ++j) {
        aa0[j] = -__expf(al0[j]) * L2E;
        aa1[j] = -__expf(al1[j]) * L2E;
        aa2[j] = -__expf(al2[j]) * L2E;
        aa3[j] = -__expf(al3[j]) * L2E;
    }
    const int t0 = c * CHKT;
    const float* dP = xz + ((size_t)b * NT + t0) * (2 * DINNER) + d;
    const u16* uhP = uh + ((size_t)b * NT + t0) * DINNER + d;
    const u16* ulP = ul + ((size_t)b * NT + t0) * DINNER + d;
    const float* bP = xdbl + ((size_t)b * NT + t0) * 128 + DTRANK;
    f32x4 h0 = {0.f,0.f,0.f,0.f}, h1 = h0, h2 = h0, h3 = h0;
    float S = 0.f;
    float dlt = dP[0];
    float uu = bf2f(uhP[0]) + bf2f(ulP[0]);
    for (int t = 0; t < CHKT; ++t) {
        float dlt_n = 0.f, uu_n = 0.f;
        if (t + 1 < CHKT) {
            dlt_n = dP[2 * DINNER];
            uu_n = bf2f(uhP[DINNER]) + bf2f(ulP[DINNER]);
        }
        f32x4 B0 = *(const f32x4*)(bP + 0);
        f32x4 B1 = *(const f32x4*)(bP + 4);
        f32x4 B2 = *(const f32x4*)(bP + 8);
        f32x4 B3 = *(const f32x4*)(bP + 12);
        float du = dlt * uu;
        S += dlt;
        h0 = exp2v(dlt * aa0) * h0 + du * B0;
        h1 = exp2v(dlt * aa1) * h1 + du * B1;
        h2 = exp2v(dlt * aa2) * h2 + du * B2;
        h3 = exp2v(dlt * aa3) * h3 + du * B3;
        dP += 2 * DINNER; uhP += DINNER; ulP += DINNER; bP += 128;
        dlt = dlt_n; uu = uu_n;
    }
    size_t a = (((size_t)(b * NCHK + c) * DINNER) + d) * DSTATE;
    *(f32x4*)(HP + a + 0)  = h0;
    *(f32x4*)(HP + a + 4)  = h1;
    *(f32x4*)(HP + a + 8)  = h2;
    *(f32x4*)(HP + a + 12) = h3;
    SS[(size_t)(b * NCHK + c) * DINNER + d] = S;
}

// ---------------- stitched: scan p2 (blocks [0,1536)) + out_w split ----------------
__global__ __launch_bounds__(256) void k_p2_osplit(float* __restrict__ HP,
    const float* __restrict__ SS, const float* __restrict__ A_log,
    const float* __restrict__ wsrc, u16* __restrict__ dh, u16* __restrict__ dl)
{
    int tid = threadIdx.x;
    if (blockIdx.x >= 1536) {
        int idx = (blockIdx.x - 1536) * 256 + tid;
        if (idx >= 4718592 / 4) return;
        float4 v = ((const float4*)wsrc)[idx];
        u16 h0 = f2bf(v.x), h1 = f2bf(v.y), h2 = f2bf(v.z), h3 = f2bf(v.w);
        u16 l0 = f2bf(v.x - bf2f(h0)), l1 = f2bf(v.y - bf2f(h1));
        u16 l2 = f2bf(v.z - bf2f(h2)), l3 = f2bf(v.w - bf2f(h3));
        uint2 hv = { (u32)h0 | ((u32)h1 << 16), (u32)h2 | ((u32)h3 << 16) };
        uint2 lv = { (u32)l0 | ((u32)l1 << 16), (u32)l2 | ((u32)l3 << 16) };
        ((uint2*)dh)[idx] = hv;
        ((uint2*)dl)[idx] = lv;
        return;
    }
    int idx = blockIdx.x * 256 + tid;
    int s = idx & (DSTATE - 1);
    int d = (idx >> 4) % DINNER;
    int b = idx / (DINNER * DSTATE);
    const float L2E = 1.44269504088896340736f;
    float aa = -__expf(A_log[d * DSTATE + s]) * L2E;
    float h = 0.f;
    #pragma unroll
    for (int c = 0; c < NCHK; ++c) {
        size_t a = (((size_t)(b * NCHK + c) * DINNER) + d) * DSTATE + s;
        float hc = HP[a];
        float P = exp2f(aa * SS[(size_t)(b * NCHK + c) * DINNER + d]);
        HP[a] = h;
        h = fmaf(P, h, hc);
    }
}

// ---------------- scan pass 3: lane-per-d chunk scan with h_init (all regs) ----------------
__global__ __launch_bounds__(256) void k_scan_p3(
    const float* __restrict__ xz,
    u16* uh, u16* ul,
    const float* __restrict__ xdbl,
    const float* __restrict__ A_log, const float* __restrict__ Dp,
    const float* __restrict__ HP)
{
    const int d = blockIdx.x * 256 + threadIdx.x;
    const int c = blockIdx.y, b = blockIdx.z;
    const float L2E = 1.44269504088896340736f;
    f32x4 al0 = *(const f32x4*)(A_log + (size_t)d * DSTATE + 0);
    f32x4 al1 = *(const f32x4*)(A_log + (size_t)d * DSTATE + 4);
    f32x4 al2 = *(const f32x4*)(A_log + (size_t)d * DSTATE + 8);
    f32x4 al3 = *(const f32x4*)(A_log + (size_t)d * DSTATE + 12);
    f32x4 aa0, aa1, aa2, aa3;
    #pragma unroll
    for (int j = 0; j < 4; ++j) {
        aa0[j] = -__expf(al0[j]) * L2E;
        aa1[j] = -__expf(al1[j]) * L2E;
        aa2[j] = -__expf(al2[j]) * L2E;
        aa3[j] = -__expf(al3[j]) * L2E;
    }
    const float dp = Dp[d];
    const int t0 = c * CHKT;
    const float* dP = xz + ((size_t)b * NT + t0) * (2 * DINNER) + d;
    const float* zP = dP + DINNER;
    const u16* uhP = uh + ((size_t)b * NT + t0) * DINNER + d;
    const u16* ulP = ul + ((size_t)b * NT + t0) * DINNER + d;
    u16* yhP = (u16*)uhP;
    u16* ylP = (u16*)ulP;
    const float* bP = xdbl + ((size_t)b * NT + t0) * 128 + DTRANK;
    size_t ha = (((size_t)(b * NCHK + c) * DINNER) + d) * DSTATE;
    f32x4 h0 = *(const f32x4*)(HP + ha + 0);
    f32x4 h1 = *(const f32x4*)(HP + ha + 4);
    f32x4 h2 = *(const f32x4*)(HP + ha + 8);
    f32x4 h3 = *(const f32x4*)(HP + ha + 12);
    float dlt = dP[0], zz = zP[0];
    float uu = bf2f(uhP[0]) + bf2f(ulP[0]);
    for (int t = 0; t < CHKT; ++t) {
        float dlt_n = 0.f, uu_n = 0.f, zz_n = 0.f;
        if (t + 1 < CHKT) {
            dlt_n = dP[2 * DINNER]; zz_n = zP[2 * DINNER];
            uu_n = bf2f(uhP[DINNER]) + bf2f(ulP[DINNER]);
        }
        f32x4 B0 = *(const f32x4*)(bP + 0);
        f32x4 B1 = *(const f32x4*)(bP + 4);
        f32x4 B2 = *(const f32x4*)(bP + 8);
        f32x4 B3 = *(const f32x4*)(bP + 12);
        f32x4 C0 = *(const f32x4*)(bP + DSTATE + 0);
        f32x4 C1 = *(const f32x4*)(bP + DSTATE + 4);
        f32x4 C2 = *(const f32x4*)(bP + DSTATE + 8);
        f32x4 C3 = *(const f32x4*)(bP + DSTATE + 12);
        float du = dlt * uu;
        h0 = exp2v(dlt * aa0) * h0 + du * B0;
        h1 = exp2v(dlt * aa1) * h1 + du * B1;
        h2 = exp2v(dlt * aa2) * h2 + du * B2;
        h3 = exp2v(dlt * aa3) * h3 + du * B3;
        f32x4 pv = h0 * C0 + h1 * C1 + h2 * C2 + h3 * C3;
        float p = (pv[0] + pv[1]) + (pv[2] + pv[3]);
        float yv = (p + uu * dp) * siluf(zz);
        u16 hh = f2bf(yv);
        yhP[0] = hh;
        ylP[0] = f2bf(yv - bf2f(hh));
        dP += 2 * DINNER; zP += 2 * DINNER;
        uhP += DINNER; ulP += DINNER; yhP += DINNER; ylP += DINNER;
        bP += 128;
        dlt = dlt_n; zz = zz_n; uu = uu_n;
    }
}

// ---------------- final fc + silu + transpose to (B,5,T) ----------------
__global__ __launch_bounds__(256) void k_fc(const float* __restrict__ hR,
    const float* __restrict__ w, const float* __restrict__ bias,
    float* __restrict__ out)
{
    int row = blockIdx.x;
    int tid = threadIdx.x;
    const float* p = hR + (size_t)row * DMODEL;
    float acc[NCLASS] = {0.f, 0.f, 0.f, 0.f, 0.f};
    #pragma unroll
    for (int j = 0; j < 6; ++j) {
        int col = tid + j * 256;
        float v = p[col];
        #pragma unroll
        for (int c = 0; c < NCLASS; ++c)
            acc[c] = fmaf(v, w[c * DMODEL + col], acc[c]);
    }
    #pragma unroll
    for (int c = 0; c < NCLASS; ++c)
        #pragma unroll
        for (int off = 1; off < 64; off <<= 1)
            acc[c] += __shfl_xor(acc[c], off);
    __shared__ float red[4][NCLASS];
    int lane = tid & 63, wv = tid >> 6;
    if (lane == 0)
        for (int c = 0; c < NCLASS; ++c) red[wv][c] = acc[c];
    __syncthreads();
    if (tid < NCLASS) {
        float s = red[0][tid] + red[1][tid] + red[2][tid] + red[3][tid] + bias[tid];
        int b = row >> 10, t = row & (NT - 1);
        out[((size_t)b * NCLASS + tid) * NT + t] = siluf(s);
    }
}

extern "C" void kernel_launch(void* const* d_in, const int* in_sizes, int n_in,
                              void* d_out, int out_size, void* d_ws, size_t ws_size,
                              hipStream_t stream)
{
    const float* x      = (const float*)d_in[0];
    const float* c1a_w  = (const float*)d_in[1];
    const float* c1a_b  = (const float*)d_in[2];
    const float* c1b_w  = (const float*)d_in[3];
    const float* c1b_b  = (const float*)d_in[4];
    const float* c1s_w  = (const float*)d_in[5];
    const float* c1s_b  = (const float*)d_in[6];
    const float* c2a_w  = (const float*)d_in[7];
    const float* c2a_b  = (const float*)d_in[8];
    const float* c2b_w  = (const float*)d_in[9];
    const float* c2b_b  = (const float*)d_in[10];
    const float* norm_w = (const float*)d_in[11];
    const float* in_w   = (const float*)d_in[12];
    const float* conv_w = (const float*)d_in[13];
    const float* conv_b = (const float*)d_in[14];
    const float* xproj_w= (const float*)d_in[15];
    const float* dt_w   = (const float*)d_in[16];
    const float* dt_b   = (const float*)d_in[17];
    const float* A_log  = (const float*)d_in[18];
    const float* Dp     = (const float*)d_in[19];
    const float* out_w  = (const float*)d_in[20];
    const float* fc_w   = (const float*)d_in[21];
    const float* fc_b   = (const float*)d_in[22];
    float* outp = (float*)d_out;
    (void)in_sizes; (void)n_in; (void)out_size; (void)ws_size;

    char* base = (char*)d_ws;
    size_t off = 0;
    auto takeB = [&](size_t bytes) { void* p = base + off; off = (off + bytes + 255) & ~(size_t)255; return p; };
    float* HCAT = (float*)takeB((size_t)NB * NDIM * NT * 4);
    float* XZ   = (float*)takeB((size_t)MROWS * 2 * DINNER * 4);
    float* RES  = (float*)takeB((size_t)MROWS * DMODEL * 4);
    u16*   XNh  = (u16*)takeB((size_t)MROWS * DMODEL * 2);
    u16*   XNl  = (u16*)takeB((size_t)MROWS * DMODEL * 2);
    u16*   Uh   = (u16*)takeB((size_t)MROWS * DINNER * 2);
    u16*   Ul   = (u16*)takeB((size_t)MROWS * DINNER * 2);
    float* XDBL = (float*)takeB((size_t)MROWS * 128 * 4);
    float* XPART= (float*)takeB((size_t)4 * MROWS * 128 * 4);
    u16*   XDh  = (u16*)takeB((size_t)MROWS * 128 * 2);
    u16*   XDl  = (u16*)takeB((size_t)MROWS * 128 * 2);
    u16*   Wh   = (u16*)takeB((size_t)9437184 * 2);
    u16*   Wl   = (u16*)takeB((size_t)9437184 * 2);
    u16*   DTh  = (u16*)takeB((size_t)DINNER * 128 * 2);
    u16*   DTl  = (u16*)takeB((size_t)DINNER * 128 * 2);
    float* HP   = (float*)takeB((size_t)NB * NCHK * DINNER * DSTATE * 4);
    float* SS   = (float*)takeB((size_t)NB * NCHK * DINNER * 4);
    u16*   CW1h = (u16*)takeB(18432);
    u16*   CW1l = (u16*)takeB(18432);
    u16*   CW2h = (u16*)takeB(18432);
    u16*   CW2l = (u16*)takeB(18432);
    u16*   CW3h = (u16*)takeB(18432);
    u16*   CW3l = (u16*)takeB(18432);
    u16*   ZPAD = (u16*)takeB(256);

    u16* T1h = (u16*)XZ;
    u16* T1l = T1h + (size_t)NB * NDIM * NT * 32;
    u16* T3h = (u16*)XZ;
    u16* T3l = T3h + (size_t)NB * NDIM * NT * 32;
    u16* P1h = Uh;
    u16* P1l = Ul;

    const int n1 = NB * NDIM * NT;
    k_prep  <<<(n1 + 255) / 256, 256, 0, stream>>>(x, HCAT, ZPAD);
    k_wconv3<<<dim3(36, 3), 256, 0, stream>>>(c1b_w, CW1h, CW1l,
                                              c2a_w, CW2h, CW2l,
                                              c2b_w, CW3h, CW3l);
    k_conv1a<<<(n1 + 255) / 256, 256, 0, stream>>>(HCAT, c1a_w, c1a_b, T1h, T1l);
    k_convmfma<0><<<dim3(16, 96, NB), 256, 0, stream>>>(
        T1h, T1l, CW1h, CW1l, HCAT, c1s_w, c1s_b, nullptr, nullptr,
        c1b_b, P1h, P1l, nullptr, ZPAD);
    k_convmfma<1><<<dim3(16, 48, NB), 256, 0, stream>>>(
        P1h, P1l, CW2h, CW2l, nullptr, nullptr, nullptr, nullptr, nullptr,
        c2a_b, T3h, T3l, nullptr, ZPAD);
    k_convmfma<2><<<dim3(16, 48, NB), 256, 0, stream>>>(
        T3h, T3l, CW3h, CW3l, nullptr, nullptr, nullptr, P1h, P1l,
        c2b_b, nullptr, nullptr, RES, ZPAD);

    for (int l = 0; l < NLAYER; ++l) {
        k_norm_insplit<<<MROWS + 9216, 256, 0, stream>>>(
            RES, norm_w + (size_t)l * DMODEL, XNh, XNl,
            in_w + (size_t)l * 2 * DINNER * DMODEL, Wh, Wl);
        k_gemm256<0, 256, 0><<<dim3(2 * DINNER / 256, MROWS / 256), 512, 0, stream>>>(
            XNh, XNl, DMODEL, Wh, Wl, DMODEL, XZ, 2 * DINNER, DMODEL);
        k_conv1d_wsplit<<<3072 + 1920, 256, 0, stream>>>(
            XZ, conv_w + (size_t)l * DINNER * 4, conv_b + (size_t)l * DINNER, Uh, Ul,
            xproj_w + (size_t)l * 128 * DINNER, Wh, Wl,
            dt_w + (size_t)l * DINNER * DTRANK, DTh, DTl);
        k_gemm_mfma<0><<<dim3(1, MROWS / 128, 4), 256, 0, stream>>>(
            Uh, Ul, DINNER, Wh, Wl, DINNER, XPART, 128, DINNER, nullptr, (size_t)MROWS * 128);
        k_reduce_split<<<(MROWS * 128 + 255) / 256, 256, 0, stream>>>(XPART, XDBL, XDh, XDl);
        k_gemm_mfma<1><<<dim3(DINNER / 128, MROWS / 128, 1), 256, 0, stream>>>(
            XDh, XDl, 128, DTh, DTl, 128, XZ, 2 * DINNER, 128,
            dt_b + (size_t)l * DINNER, 0);
        k_scan_p1<<<dim3(DINNER / 256, NCHK, NB), 256, 0, stream>>>(
            XZ, Uh, Ul, XDBL, A_log + (size_t)l * DINNER * DSTATE, HP, SS);
        k_p2_osplit<<<1536 + 4608, 256, 0, stream>>>(
            HP, SS, A_log + (size_t)l * DINNER * DSTATE,
            out_w + (size_t)l * DMODEL * DINNER, Wh, Wl);
        k_scan_p3<<<dim3(DINNER / 256, NCHK, NB), 256, 0, stream>>>(
            XZ, Uh, Ul, XDBL, A_log + (size_t)l * DINNER * DSTATE,
            Dp + (size_t)l * DINNER, HP);
        k_gemm256<2, 192, 1><<<dim3(DMODEL / 192, MROWS / 256), 512, 0, stream>>>(
            Uh, Ul, DINNER, Wh, Wl, DINNER, RES, DMODEL, DINNER);
    }
    k_fc<<<MROWS, 256, 0, stream>>>(RES, fc_w, fc_b, outp);
}